// Round 1
// baseline (306.090 us; speedup 1.0000x reference)
//
#include <hip/hip_runtime.h>
#include <hip/hip_bf16.h>

#define TWO_B 4096
#define DIM_ 4096
#define NT 32  // 4096/128 tiles per dim

typedef __attribute__((ext_vector_type(8))) short bf16x8;
typedef __attribute__((ext_vector_type(4))) float f32x4;

static __device__ __forceinline__ unsigned short f2bf(float x) {
    return __builtin_bit_cast(unsigned short, __float2bfloat16(x));
}

static __device__ __forceinline__ float waveReduceSum(float v) {
    v += __shfl_xor(v, 1);  v += __shfl_xor(v, 2);  v += __shfl_xor(v, 4);
    v += __shfl_xor(v, 8);  v += __shfl_xor(v, 16); v += __shfl_xor(v, 32);
    return v;
}
static __device__ __forceinline__ float waveReduceMax(float v) {
    v = fmaxf(v, __shfl_xor(v, 1));  v = fmaxf(v, __shfl_xor(v, 2));
    v = fmaxf(v, __shfl_xor(v, 4));  v = fmaxf(v, __shfl_xor(v, 8));
    v = fmaxf(v, __shfl_xor(v, 16)); v = fmaxf(v, __shfl_xor(v, 32));
    return v;
}

// -------- Phase 1: per-row stats (KD, MSE, norms). One block per row pair b.
__global__ __launch_bounds__(256) void row_stats(
    const float* __restrict__ et, const float* __restrict__ es,
    float* __restrict__ rinv, float* __restrict__ accs)
{
    const int b = blockIdx.x;
    const int tid = threadIdx.x;
    const int wid = tid >> 6;

    const float4* tp = (const float4*)(et + (size_t)b * DIM_);
    const float4* sp = (const float4*)(es + (size_t)b * DIM_);
    float4 tv[4], sv[4];
#pragma unroll
    for (int i = 0; i < 4; ++i) { tv[i] = tp[tid + 256 * i]; sv[i] = sp[tid + 256 * i]; }

    float mt = -1e30f, ms = -1e30f, nt2 = 0.f, ns2 = 0.f, msep = 0.f;
#pragma unroll
    for (int i = 0; i < 4; ++i) {
        const float* tx = (const float*)&tv[i];
        const float* sx = (const float*)&sv[i];
#pragma unroll
        for (int j = 0; j < 4; ++j) {
            float a = tx[j], c = sx[j];
            mt = fmaxf(mt, a); ms = fmaxf(ms, c);
            nt2 += a * a; ns2 += c * c;
            float d = c - a; msep += d * d;
        }
    }
    mt = waveReduceMax(mt); ms = waveReduceMax(ms);
    __shared__ float smx[4], sms[4];
    if ((tid & 63) == 0) { smx[wid] = mt; sms[wid] = ms; }
    __syncthreads();
    mt = fmaxf(fmaxf(smx[0], smx[1]), fmaxf(smx[2], smx[3]));
    ms = fmaxf(fmaxf(sms[0], sms[1]), fmaxf(sms[2], sms[3]));

    float se_t = 0.f, st = 0.f, sx_ = 0.f, se_s = 0.f;
#pragma unroll
    for (int i = 0; i < 4; ++i) {
        const float* tx = (const float*)&tv[i];
        const float* sx = (const float*)&sv[i];
#pragma unroll
        for (int j = 0; j < 4; ++j) {
            float a = tx[j], c = sx[j];
            float e = __expf(a - mt);
            se_t += e; st += e * a; sx_ += e * c;
            se_s += __expf(c - ms);
        }
    }
    float v0 = waveReduceSum(se_t), v1 = waveReduceSum(st), v2 = waveReduceSum(sx_);
    float v3 = waveReduceSum(se_s), v4 = waveReduceSum(nt2), v5 = waveReduceSum(ns2);
    float v6 = waveReduceSum(msep);
    __shared__ float sred[7][4];
    if ((tid & 63) == 0) {
        sred[0][wid] = v0; sred[1][wid] = v1; sred[2][wid] = v2; sred[3][wid] = v3;
        sred[4][wid] = v4; sred[5][wid] = v5; sred[6][wid] = v6;
    }
    __syncthreads();
    if (tid == 0) {
        float r[7];
#pragma unroll
        for (int k = 0; k < 7; ++k) r[k] = sred[k][0] + sred[k][1] + sred[k][2] + sred[k][3];
        float lse_t = mt + logf(r[0]);
        float lse_s = ms + logf(r[3]);
        float kd = (r[1] - r[2]) / r[0] - lse_t + lse_s;
        atomicAdd(&accs[0], kd);
        atomicAdd(&accs[1], r[6]);
        rinv[b]          = 1.f / fmaxf(sqrtf(r[4]), 1e-8f);
        rinv[b + 2048]   = 1.f / fmaxf(sqrtf(r[5]), 1e-8f);
    }
}

// -------- Phase 2: contrastive GEMM over upper-triangular 128x128 tiles.
__global__ __launch_bounds__(256) void cont_gemm(
    const float* __restrict__ et, const float* __restrict__ es,
    const float* __restrict__ rinv, float* __restrict__ rowsum,
    float* __restrict__ pos)
{
    // linear -> (bi, bj) with bi <= bj
    int t = blockIdx.x;
    int bi = 0;
    while (t >= (NT - bi)) { t -= (NT - bi); ++bi; }
    const int bj = bi + t;
    const int brow = bi * 128, bcol = bj * 128;

    __shared__ unsigned short As[128 * 64];
    __shared__ unsigned short Bs[128 * 64];

    const int tid = threadIdx.x;
    const int lane = tid & 63;
    const int wid = tid >> 6;
    const int wm = wid >> 1, wn = wid & 1;

    // staging assignment: 256 threads cover 128 rows x 16 float4 cols, 8 iters
    const int srow = tid >> 4;  // 0..15
    const int sf4 = tid & 15;   // 0..15

    const float* pA[8]; const float* pB[8];
    float riA[8], riB[8];
#pragma unroll
    for (int it = 0; it < 8; ++it) {
        int r = srow + it * 16;
        int ga = brow + r;
        int gb = bcol + r;
        pA[it] = (ga < 2048) ? (et + (size_t)ga * DIM_) : (es + (size_t)(ga - 2048) * DIM_);
        pB[it] = (gb < 2048) ? (et + (size_t)gb * DIM_) : (es + (size_t)(gb - 2048) * DIM_);
        riA[it] = rinv[ga]; riB[it] = rinv[gb];
    }

    f32x4 acc[4][4] = {};

    for (int kt = 0; kt < DIM_; kt += 64) {
        __syncthreads();
#pragma unroll
        for (int it = 0; it < 8; ++it) {
            int r = srow + it * 16;
            int swz = (r & 7) << 4;
            int bo = (r * 128 + sf4 * 8) ^ swz;
            {
                float4 v = *(const float4*)(pA[it] + kt + sf4 * 4);
                float ri = riA[it];
                ushort4 pk = make_ushort4(f2bf(v.x * ri), f2bf(v.y * ri),
                                          f2bf(v.z * ri), f2bf(v.w * ri));
                *(ushort4*)((char*)As + bo) = pk;
            }
            {
                float4 v = *(const float4*)(pB[it] + kt + sf4 * 4);
                float ri = riB[it];
                ushort4 pk = make_ushort4(f2bf(v.x * ri), f2bf(v.y * ri),
                                          f2bf(v.z * ri), f2bf(v.w * ri));
                *(ushort4*)((char*)Bs + bo) = pk;
            }
        }
        __syncthreads();
#pragma unroll
        for (int ks = 0; ks < 2; ++ks) {
            bf16x8 af[4], bfr[4];
            const int li = lane & 15;
            const int kb = ks * 64 + (lane >> 4) * 16;  // byte offset within row
#pragma unroll
            for (int m = 0; m < 4; ++m) {
                int r = wm * 64 + m * 16 + li;
                int off = (r * 128 + kb) ^ ((r & 7) << 4);
                af[m] = *(const bf16x8*)((const char*)As + off);
            }
#pragma unroll
            for (int n = 0; n < 4; ++n) {
                int r = wn * 64 + n * 16 + li;
                int off = (r * 128 + kb) ^ ((r & 7) << 4);
                bfr[n] = *(const bf16x8*)((const char*)Bs + off);
            }
#pragma unroll
            for (int m = 0; m < 4; ++m)
#pragma unroll
                for (int n = 0; n < 4; ++n)
                    acc[m][n] = __builtin_amdgcn_mfma_f32_16x16x32_bf16(
                        af[m], bfr[n], acc[m][n], 0, 0, 0);
        }
    }

    // -------- epilogue: exp, diagonal mask, positives, row/col sums
    const bool diag = (bi == bj);
    const bool posT = (bcol == (brow ^ 2048));
    const int li = lane & 15;
    const int lg = lane >> 4;
    float cs[4] = {0.f, 0.f, 0.f, 0.f};
#pragma unroll
    for (int m = 0; m < 4; ++m) {
#pragma unroll
        for (int q = 0; q < 4; ++q) {
            int lr = wm * 64 + m * 16 + lg * 4 + q;  // local row
            float rsum = 0.f;
#pragma unroll
            for (int n = 0; n < 4; ++n) {
                int lc = wn * 64 + n * 16 + li;  // local col
                float v = acc[m][n][q];
                if (posT && lc == lr) { pos[brow + lr] = v; pos[bcol + lc] = v; }
                float e = (diag && lc == lr) ? 0.f : __expf(2.0f * v);
                rsum += e;
                cs[n] += e;
            }
            rsum += __shfl_xor(rsum, 1);
            rsum += __shfl_xor(rsum, 2);
            rsum += __shfl_xor(rsum, 4);
            rsum += __shfl_xor(rsum, 8);
            if (li == 0) atomicAdd(&rowsum[brow + lr], rsum);
        }
    }
    if (!diag) {
#pragma unroll
        for (int n = 0; n < 4; ++n) {
            float v = cs[n];
            v += __shfl_xor(v, 16);
            v += __shfl_xor(v, 32);
            if (lg == 0) atomicAdd(&rowsum[bcol + wn * 64 + n * 16 + li], v);
        }
    }
}

// -------- Phase 3: finalize scalar loss
__global__ __launch_bounds__(256) void finalize(
    const float* __restrict__ rowsum, const float* __restrict__ pos,
    const float* __restrict__ accs, float* __restrict__ out)
{
    const int tid = threadIdx.x;
    float c = 0.f;
    for (int i = tid; i < TWO_B; i += 256)
        c += logf(rowsum[i]) - 2.0f * pos[i];
    c = waveReduceSum(c);
    __shared__ float sm[4];
    if ((tid & 63) == 0) sm[tid >> 6] = c;
    __syncthreads();
    if (tid == 0) {
        float cont = (sm[0] + sm[1] + sm[2] + sm[3]) / 4096.0f;
        out[0] = cont + accs[0] / 2048.0f + accs[1] / (2048.0f * 4096.0f);
    }
}

extern "C" void kernel_launch(void* const* d_in, const int* in_sizes, int n_in,
                              void* d_out, int out_size, void* d_ws, size_t ws_size,
                              hipStream_t stream) {
    const float* et = (const float*)d_in[0];
    const float* es = (const float*)d_in[1];
    float* ws = (float*)d_ws;
    float* rowsum = ws;                       // 4096 floats
    float* accs = ws + 4096;                  // 2 floats (kd, mse), padded to 16
    float* pos = ws + 4096 + 16;              // 4096 floats
    float* rinv = ws + 4096 + 16 + 4096;      // 4096 floats

    hipMemsetAsync(rowsum, 0, (4096 + 16) * sizeof(float), stream);
    hipLaunchKernelGGL(row_stats, dim3(2048), dim3(256), 0, stream, et, es, rinv, accs);
    hipLaunchKernelGGL(cont_gemm, dim3(528), dim3(256), 0, stream, et, es, rinv, rowsum, pos);
    hipLaunchKernelGGL(finalize, dim3(1), dim3(256), 0, stream, rowsum, pos, accs, (float*)d_out);
}

// Round 2
// 223.954 us; speedup vs baseline: 1.3668x; 1.3668x over previous
//
#include <hip/hip_runtime.h>
#include <hip/hip_bf16.h>

#define TWO_B 4096
#define DIM_ 4096
#define NT 32  // 4096/128 tiles per dim

typedef __attribute__((ext_vector_type(8))) short bf16x8;
typedef __attribute__((ext_vector_type(4))) float f32x4;

static __device__ __forceinline__ unsigned short f2bf(float x) {
    return __builtin_bit_cast(unsigned short, __float2bfloat16(x));
}

static __device__ __forceinline__ float waveReduceSum(float v) {
    v += __shfl_xor(v, 1);  v += __shfl_xor(v, 2);  v += __shfl_xor(v, 4);
    v += __shfl_xor(v, 8);  v += __shfl_xor(v, 16); v += __shfl_xor(v, 32);
    return v;
}
static __device__ __forceinline__ float waveReduceMax(float v) {
    v = fmaxf(v, __shfl_xor(v, 1));  v = fmaxf(v, __shfl_xor(v, 2));
    v = fmaxf(v, __shfl_xor(v, 4));  v = fmaxf(v, __shfl_xor(v, 8));
    v = fmaxf(v, __shfl_xor(v, 16)); v = fmaxf(v, __shfl_xor(v, 32));
    return v;
}

// -------- Phase 1: per-row stats (KD, MSE, norms) + optional z (bf16) write.
__global__ __launch_bounds__(256) void row_stats(
    const float* __restrict__ et, const float* __restrict__ es,
    float* __restrict__ rinv, float* __restrict__ accs,
    unsigned short* __restrict__ z)
{
    const int b = blockIdx.x;
    const int tid = threadIdx.x;
    const int wid = tid >> 6;

    const float4* tp = (const float4*)(et + (size_t)b * DIM_);
    const float4* sp = (const float4*)(es + (size_t)b * DIM_);
    float4 tv[4], sv[4];
#pragma unroll
    for (int i = 0; i < 4; ++i) { tv[i] = tp[tid + 256 * i]; sv[i] = sp[tid + 256 * i]; }

    float mt = -1e30f, ms = -1e30f, nt2 = 0.f, ns2 = 0.f, msep = 0.f;
#pragma unroll
    for (int i = 0; i < 4; ++i) {
        const float* tx = (const float*)&tv[i];
        const float* sx = (const float*)&sv[i];
#pragma unroll
        for (int j = 0; j < 4; ++j) {
            float a = tx[j], c = sx[j];
            mt = fmaxf(mt, a); ms = fmaxf(ms, c);
            nt2 += a * a; ns2 += c * c;
            float d = c - a; msep += d * d;
        }
    }
    mt = waveReduceMax(mt); ms = waveReduceMax(ms);
    __shared__ float smx[4], sms[4];
    if ((tid & 63) == 0) { smx[wid] = mt; sms[wid] = ms; }
    __syncthreads();
    mt = fmaxf(fmaxf(smx[0], smx[1]), fmaxf(smx[2], smx[3]));
    ms = fmaxf(fmaxf(sms[0], sms[1]), fmaxf(sms[2], sms[3]));

    float se_t = 0.f, st = 0.f, sx_ = 0.f, se_s = 0.f;
#pragma unroll
    for (int i = 0; i < 4; ++i) {
        const float* tx = (const float*)&tv[i];
        const float* sx = (const float*)&sv[i];
#pragma unroll
        for (int j = 0; j < 4; ++j) {
            float a = tx[j], c = sx[j];
            float e = __expf(a - mt);
            se_t += e; st += e * a; sx_ += e * c;
            se_s += __expf(c - ms);
        }
    }
    float v0 = waveReduceSum(se_t), v1 = waveReduceSum(st), v2 = waveReduceSum(sx_);
    float v3 = waveReduceSum(se_s), v4 = waveReduceSum(nt2), v5 = waveReduceSum(ns2);
    float v6 = waveReduceSum(msep);
    __shared__ float sred[7][4];
    if ((tid & 63) == 0) {
        sred[0][wid] = v0; sred[1][wid] = v1; sred[2][wid] = v2; sred[3][wid] = v3;
        sred[4][wid] = v4; sred[5][wid] = v5; sred[6][wid] = v6;
    }
    __syncthreads();
    const float rT = sred[4][0] + sred[4][1] + sred[4][2] + sred[4][3];
    const float rS = sred[5][0] + sred[5][1] + sred[5][2] + sred[5][3];
    const float rinvT = 1.f / fmaxf(sqrtf(rT), 1e-8f);
    const float rinvS = 1.f / fmaxf(sqrtf(rS), 1e-8f);

    if (tid == 0) {
        float r0 = sred[0][0] + sred[0][1] + sred[0][2] + sred[0][3];
        float r1 = sred[1][0] + sred[1][1] + sred[1][2] + sred[1][3];
        float r2 = sred[2][0] + sred[2][1] + sred[2][2] + sred[2][3];
        float r3 = sred[3][0] + sred[3][1] + sred[3][2] + sred[3][3];
        float r6 = sred[6][0] + sred[6][1] + sred[6][2] + sred[6][3];
        float lse_t = mt + logf(r0);
        float lse_s = ms + logf(r3);
        float kd = (r1 - r2) / r0 - lse_t + lse_s;
        atomicAdd(&accs[0], kd);
        atomicAdd(&accs[1], r6);
        rinv[b]        = rinvT;
        rinv[b + 2048] = rinvS;
    }

    if (z) {
        unsigned short* zt = z + (size_t)b * DIM_;
        unsigned short* zs = z + (size_t)(b + 2048) * DIM_;
#pragma unroll
        for (int i = 0; i < 4; ++i) {
            const float* tx = (const float*)&tv[i];
            const float* sx = (const float*)&sv[i];
            ushort4 pt = make_ushort4(f2bf(tx[0] * rinvT), f2bf(tx[1] * rinvT),
                                      f2bf(tx[2] * rinvT), f2bf(tx[3] * rinvT));
            ushort4 ps = make_ushort4(f2bf(sx[0] * rinvS), f2bf(sx[1] * rinvS),
                                      f2bf(sx[2] * rinvS), f2bf(sx[3] * rinvS));
            *(ushort4*)(zt + 4 * (tid + 256 * i)) = pt;
            *(ushort4*)(zs + 4 * (tid + 256 * i)) = ps;
        }
    }
}

// -------- Phase 2 (fast): bf16 GEMM on precomputed z, global_load_lds staging.
// LDS layout: linear [128 rows][64 cols] bf16, 128 B/row. Swizzle applied to
// the per-lane GLOBAL source and to the ds_read offset (same involution):
// byte_off ^= (row&7)<<4.
__global__ __launch_bounds__(256) void cont_gemm2(
    const unsigned short* __restrict__ z,
    float* __restrict__ rowsum, float* __restrict__ pos)
{
    // XCD-aware swizzle: 528 = 8 * 66 exactly -> simple bijective remap
    const int bid = blockIdx.x;
    int t = (bid & 7) * 66 + (bid >> 3);
    int bi = 0;
    while (t >= (NT - bi)) { t -= (NT - bi); ++bi; }
    const int bj = bi + t;
    const int brow = bi * 128, bcol = bj * 128;

    __shared__ unsigned short As[128 * 64];
    __shared__ unsigned short Bs[128 * 64];

    const int tid = threadIdx.x;
    const int lane = tid & 63;
    const int wid = tid >> 6;
    const int wm = wid >> 1, wn = wid & 1;

    // staging: each wave covers 32 rows (4 issues x 8 rows); lane -> row,block
    const int srow_base = wid * 32;
    const int lrow = lane >> 3;   // 0..7
    const int lblk = lane & 7;    // 16B-block within 128B row

    f32x4 acc[4][4] = {};

    for (int kt = 0; kt < DIM_; kt += 64) {
        __syncthreads();
#pragma unroll
        for (int i = 0; i < 4; ++i) {
            const int r = srow_base + i * 8 + lrow;            // local row 0..127
            const int ce = ((lblk ^ (r & 7)) << 3);            // element offset in row seg
            const unsigned short* srcA = z + (size_t)(brow + r) * DIM_ + kt + ce;
            const unsigned short* srcB = z + (size_t)(bcol + r) * DIM_ + kt + ce;
            unsigned short* dstA = As + (srow_base + i * 8) * 64;  // wave-uniform
            unsigned short* dstB = Bs + (srow_base + i * 8) * 64;
            __builtin_amdgcn_global_load_lds(
                (const __attribute__((address_space(1))) unsigned int*)srcA,
                (__attribute__((address_space(3))) unsigned int*)dstA, 16, 0, 0);
            __builtin_amdgcn_global_load_lds(
                (const __attribute__((address_space(1))) unsigned int*)srcB,
                (__attribute__((address_space(3))) unsigned int*)dstB, 16, 0, 0);
        }
        __syncthreads();
#pragma unroll
        for (int ks = 0; ks < 2; ++ks) {
            bf16x8 af[4], bfr[4];
            const int li = lane & 15;
            const int kb = ks * 64 + (lane >> 4) * 16;  // byte offset within row
#pragma unroll
            for (int m = 0; m < 4; ++m) {
                int r = wm * 64 + m * 16 + li;
                int off = (r * 128 + kb) ^ ((r & 7) << 4);
                af[m] = *(const bf16x8*)((const char*)As + off);
            }
#pragma unroll
            for (int n = 0; n < 4; ++n) {
                int r = wn * 64 + n * 16 + li;
                int off = (r * 128 + kb) ^ ((r & 7) << 4);
                bfr[n] = *(const bf16x8*)((const char*)Bs + off);
            }
#pragma unroll
            for (int m = 0; m < 4; ++m)
#pragma unroll
                for (int n = 0; n < 4; ++n)
                    acc[m][n] = __builtin_amdgcn_mfma_f32_16x16x32_bf16(
                        af[m], bfr[n], acc[m][n], 0, 0, 0);
        }
    }

    // -------- epilogue: exp, diagonal mask, positives, row/col sums
    const bool diag = (bi == bj);
    const bool posT = (bcol == (brow ^ 2048));
    const int li = lane & 15;
    const int lg = lane >> 4;
    float cs[4] = {0.f, 0.f, 0.f, 0.f};
#pragma unroll
    for (int m = 0; m < 4; ++m) {
#pragma unroll
        for (int q = 0; q < 4; ++q) {
            int lr = wm * 64 + m * 16 + lg * 4 + q;  // local row
            float rsum = 0.f;
#pragma unroll
            for (int n = 0; n < 4; ++n) {
                int lc = wn * 64 + n * 16 + li;  // local col
                float v = acc[m][n][q];
                if (posT && lc == lr) { pos[brow + lr] = v; pos[bcol + lc] = v; }
                float e = (diag && lc == lr) ? 0.f : __expf(2.0f * v);
                rsum += e;
                cs[n] += e;
            }
            rsum += __shfl_xor(rsum, 1);
            rsum += __shfl_xor(rsum, 2);
            rsum += __shfl_xor(rsum, 4);
            rsum += __shfl_xor(rsum, 8);
            if (li == 0) atomicAdd(&rowsum[brow + lr], rsum);
        }
    }
    if (!diag) {
#pragma unroll
        for (int n = 0; n < 4; ++n) {
            float v = cs[n];
            v += __shfl_xor(v, 16);
            v += __shfl_xor(v, 32);
            if (lg == 0) atomicAdd(&rowsum[bcol + wn * 64 + n * 16 + li], v);
        }
    }
}

// -------- Phase 2 (fallback, verified round-1 path): on-the-fly normalize.
__global__ __launch_bounds__(256) void cont_gemm(
    const float* __restrict__ et, const float* __restrict__ es,
    const float* __restrict__ rinv, float* __restrict__ rowsum,
    float* __restrict__ pos)
{
    int t = blockIdx.x;
    int bi = 0;
    while (t >= (NT - bi)) { t -= (NT - bi); ++bi; }
    const int bj = bi + t;
    const int brow = bi * 128, bcol = bj * 128;

    __shared__ unsigned short As[128 * 64];
    __shared__ unsigned short Bs[128 * 64];

    const int tid = threadIdx.x;
    const int lane = tid & 63;
    const int wid = tid >> 6;
    const int wm = wid >> 1, wn = wid & 1;

    const int srow = tid >> 4;
    const int sf4 = tid & 15;

    const float* pA[8]; const float* pB[8];
    float riA[8], riB[8];
#pragma unroll
    for (int it = 0; it < 8; ++it) {
        int r = srow + it * 16;
        int ga = brow + r;
        int gb = bcol + r;
        pA[it] = (ga < 2048) ? (et + (size_t)ga * DIM_) : (es + (size_t)(ga - 2048) * DIM_);
        pB[it] = (gb < 2048) ? (et + (size_t)gb * DIM_) : (es + (size_t)(gb - 2048) * DIM_);
        riA[it] = rinv[ga]; riB[it] = rinv[gb];
    }

    f32x4 acc[4][4] = {};

    for (int kt = 0; kt < DIM_; kt += 64) {
        __syncthreads();
#pragma unroll
        for (int it = 0; it < 8; ++it) {
            int r = srow + it * 16;
            int swz = (r & 7) << 4;
            int bo = (r * 128 + sf4 * 8) ^ swz;
            {
                float4 v = *(const float4*)(pA[it] + kt + sf4 * 4);
                float ri = riA[it];
                ushort4 pk = make_ushort4(f2bf(v.x * ri), f2bf(v.y * ri),
                                          f2bf(v.z * ri), f2bf(v.w * ri));
                *(ushort4*)((char*)As + bo) = pk;
            }
            {
                float4 v = *(const float4*)(pB[it] + kt + sf4 * 4);
                float ri = riB[it];
                ushort4 pk = make_ushort4(f2bf(v.x * ri), f2bf(v.y * ri),
                                          f2bf(v.z * ri), f2bf(v.w * ri));
                *(ushort4*)((char*)Bs + bo) = pk;
            }
        }
        __syncthreads();
#pragma unroll
        for (int ks = 0; ks < 2; ++ks) {
            bf16x8 af[4], bfr[4];
            const int li = lane & 15;
            const int kb = ks * 64 + (lane >> 4) * 16;
#pragma unroll
            for (int m = 0; m < 4; ++m) {
                int r = wm * 64 + m * 16 + li;
                int off = (r * 128 + kb) ^ ((r & 7) << 4);
                af[m] = *(const bf16x8*)((const char*)As + off);
            }
#pragma unroll
            for (int n = 0; n < 4; ++n) {
                int r = wn * 64 + n * 16 + li;
                int off = (r * 128 + kb) ^ ((r & 7) << 4);
                bfr[n] = *(const bf16x8*)((const char*)Bs + off);
            }
#pragma unroll
            for (int m = 0; m < 4; ++m)
#pragma unroll
                for (int n = 0; n < 4; ++n)
                    acc[m][n] = __builtin_amdgcn_mfma_f32_16x16x32_bf16(
                        af[m], bfr[n], acc[m][n], 0, 0, 0);
        }
    }

    const bool diag = (bi == bj);
    const bool posT = (bcol == (brow ^ 2048));
    const int li = lane & 15;
    const int lg = lane >> 4;
    float cs[4] = {0.f, 0.f, 0.f, 0.f};
#pragma unroll
    for (int m = 0; m < 4; ++m) {
#pragma unroll
        for (int q = 0; q < 4; ++q) {
            int lr = wm * 64 + m * 16 + lg * 4 + q;
            float rsum = 0.f;
#pragma unroll
            for (int n = 0; n < 4; ++n) {
                int lc = wn * 64 + n * 16 + li;
                float v = acc[m][n][q];
                if (posT && lc == lr) { pos[brow + lr] = v; pos[bcol + lc] = v; }
                float e = (diag && lc == lr) ? 0.f : __expf(2.0f * v);
                rsum += e;
                cs[n] += e;
            }
            rsum += __shfl_xor(rsum, 1);
            rsum += __shfl_xor(rsum, 2);
            rsum += __shfl_xor(rsum, 4);
            rsum += __shfl_xor(rsum, 8);
            if (li == 0) atomicAdd(&rowsum[brow + lr], rsum);
        }
    }
    if (!diag) {
#pragma unroll
        for (int n = 0; n < 4; ++n) {
            float v = cs[n];
            v += __shfl_xor(v, 16);
            v += __shfl_xor(v, 32);
            if (lg == 0) atomicAdd(&rowsum[bcol + wn * 64 + n * 16 + li], v);
        }
    }
}

// -------- Phase 3: finalize scalar loss
__global__ __launch_bounds__(256) void finalize(
    const float* __restrict__ rowsum, const float* __restrict__ pos,
    const float* __restrict__ accs, float* __restrict__ out)
{
    const int tid = threadIdx.x;
    float c = 0.f;
    for (int i = tid; i < TWO_B; i += 256)
        c += logf(rowsum[i]) - 2.0f * pos[i];
    c = waveReduceSum(c);
    __shared__ float sm[4];
    if ((tid & 63) == 0) sm[tid >> 6] = c;
    __syncthreads();
    if (tid == 0) {
        float cont = (sm[0] + sm[1] + sm[2] + sm[3]) / 4096.0f;
        out[0] = cont + accs[0] / 2048.0f + accs[1] / (2048.0f * 4096.0f);
    }
}

extern "C" void kernel_launch(void* const* d_in, const int* in_sizes, int n_in,
                              void* d_out, int out_size, void* d_ws, size_t ws_size,
                              hipStream_t stream) {
    const float* et = (const float*)d_in[0];
    const float* es = (const float*)d_in[1];

    const size_t Z_BYTES = (size_t)TWO_B * DIM_ * 2;  // 32 MiB bf16
    const size_t SMALL_FLOATS = 4096 + 16 + 4096 + 4096;
    const bool fast = ws_size >= Z_BYTES + SMALL_FLOATS * sizeof(float);

    if (fast) {
        unsigned short* z = (unsigned short*)d_ws;
        float* smallf = (float*)((char*)d_ws + Z_BYTES);
        float* rowsum = smallf;
        float* accs = smallf + 4096;
        float* pos = smallf + 4096 + 16;
        float* rinv = smallf + 4096 + 16 + 4096;
        hipMemsetAsync(rowsum, 0, (4096 + 16) * sizeof(float), stream);
        hipLaunchKernelGGL(row_stats, dim3(2048), dim3(256), 0, stream, et, es, rinv, accs, z);
        hipLaunchKernelGGL(cont_gemm2, dim3(528), dim3(256), 0, stream, z, rowsum, pos);
        hipLaunchKernelGGL(finalize, dim3(1), dim3(256), 0, stream, rowsum, pos, accs, (float*)d_out);
    } else {
        float* ws = (float*)d_ws;
        float* rowsum = ws;
        float* accs = ws + 4096;
        float* pos = ws + 4096 + 16;
        float* rinv = ws + 4096 + 16 + 4096;
        hipMemsetAsync(rowsum, 0, (4096 + 16) * sizeof(float), stream);
        hipLaunchKernelGGL(row_stats, dim3(2048), dim3(256), 0, stream, et, es, rinv, accs,
                           (unsigned short*)nullptr);
        hipLaunchKernelGGL(cont_gemm, dim3(528), dim3(256), 0, stream, et, es, rinv, rowsum, pos);
        hipLaunchKernelGGL(finalize, dim3(1), dim3(256), 0, stream, rowsum, pos, accs, (float*)d_out);
    }
}

// Round 3
// 201.114 us; speedup vs baseline: 1.5220x; 1.1136x over previous
//
#include <hip/hip_runtime.h>
#include <hip/hip_bf16.h>

#define TWO_B 4096
#define DIM_ 4096

typedef __attribute__((ext_vector_type(8))) short bf16x8;
typedef __attribute__((ext_vector_type(4))) float f32x4;

static __device__ __forceinline__ unsigned short f2bf(float x) {
    return __builtin_bit_cast(unsigned short, __float2bfloat16(x));
}

static __device__ __forceinline__ float waveReduceSum(float v) {
    v += __shfl_xor(v, 1);  v += __shfl_xor(v, 2);  v += __shfl_xor(v, 4);
    v += __shfl_xor(v, 8);  v += __shfl_xor(v, 16); v += __shfl_xor(v, 32);
    return v;
}
static __device__ __forceinline__ float waveReduceMax(float v) {
    v = fmaxf(v, __shfl_xor(v, 1));  v = fmaxf(v, __shfl_xor(v, 2));
    v = fmaxf(v, __shfl_xor(v, 4));  v = fmaxf(v, __shfl_xor(v, 8));
    v = fmaxf(v, __shfl_xor(v, 16)); v = fmaxf(v, __shfl_xor(v, 32));
    return v;
}

// -------- Phase 1: per-row stats (KD, MSE, norms) + z (bf16) write.
__global__ __launch_bounds__(256) void row_stats(
    const float* __restrict__ et, const float* __restrict__ es,
    float* __restrict__ rinv, float* __restrict__ accs,
    unsigned short* __restrict__ z)
{
    const int b = blockIdx.x;
    const int tid = threadIdx.x;
    const int wid = tid >> 6;

    const float4* tp = (const float4*)(et + (size_t)b * DIM_);
    const float4* sp = (const float4*)(es + (size_t)b * DIM_);
    float4 tv[4], sv[4];
#pragma unroll
    for (int i = 0; i < 4; ++i) { tv[i] = tp[tid + 256 * i]; sv[i] = sp[tid + 256 * i]; }

    float mt = -1e30f, ms = -1e30f, nt2 = 0.f, ns2 = 0.f, msep = 0.f;
#pragma unroll
    for (int i = 0; i < 4; ++i) {
        const float* tx = (const float*)&tv[i];
        const float* sx = (const float*)&sv[i];
#pragma unroll
        for (int j = 0; j < 4; ++j) {
            float a = tx[j], c = sx[j];
            mt = fmaxf(mt, a); ms = fmaxf(ms, c);
            nt2 += a * a; ns2 += c * c;
            float d = c - a; msep += d * d;
        }
    }
    mt = waveReduceMax(mt); ms = waveReduceMax(ms);
    __shared__ float smx[4], sms[4];
    if ((tid & 63) == 0) { smx[wid] = mt; sms[wid] = ms; }
    __syncthreads();
    mt = fmaxf(fmaxf(smx[0], smx[1]), fmaxf(smx[2], smx[3]));
    ms = fmaxf(fmaxf(sms[0], sms[1]), fmaxf(sms[2], sms[3]));

    float se_t = 0.f, st = 0.f, sx_ = 0.f, se_s = 0.f;
#pragma unroll
    for (int i = 0; i < 4; ++i) {
        const float* tx = (const float*)&tv[i];
        const float* sx = (const float*)&sv[i];
#pragma unroll
        for (int j = 0; j < 4; ++j) {
            float a = tx[j], c = sx[j];
            float e = __expf(a - mt);
            se_t += e; st += e * a; sx_ += e * c;
            se_s += __expf(c - ms);
        }
    }
    float v0 = waveReduceSum(se_t), v1 = waveReduceSum(st), v2 = waveReduceSum(sx_);
    float v3 = waveReduceSum(se_s), v4 = waveReduceSum(nt2), v5 = waveReduceSum(ns2);
    float v6 = waveReduceSum(msep);
    __shared__ float sred[7][4];
    if ((tid & 63) == 0) {
        sred[0][wid] = v0; sred[1][wid] = v1; sred[2][wid] = v2; sred[3][wid] = v3;
        sred[4][wid] = v4; sred[5][wid] = v5; sred[6][wid] = v6;
    }
    __syncthreads();
    const float rT = sred[4][0] + sred[4][1] + sred[4][2] + sred[4][3];
    const float rS = sred[5][0] + sred[5][1] + sred[5][2] + sred[5][3];
    const float rinvT = 1.f / fmaxf(sqrtf(rT), 1e-8f);
    const float rinvS = 1.f / fmaxf(sqrtf(rS), 1e-8f);

    if (tid == 0) {
        float r0 = sred[0][0] + sred[0][1] + sred[0][2] + sred[0][3];
        float r1 = sred[1][0] + sred[1][1] + sred[1][2] + sred[1][3];
        float r2 = sred[2][0] + sred[2][1] + sred[2][2] + sred[2][3];
        float r3 = sred[3][0] + sred[3][1] + sred[3][2] + sred[3][3];
        float r6 = sred[6][0] + sred[6][1] + sred[6][2] + sred[6][3];
        float lse_t = mt + logf(r0);
        float lse_s = ms + logf(r3);
        float kd = (r1 - r2) / r0 - lse_t + lse_s;
        atomicAdd(&accs[0], kd);
        atomicAdd(&accs[1], r6);
        rinv[b]        = rinvT;
        rinv[b + 2048] = rinvS;
    }

    if (z) {
        unsigned short* zt = z + (size_t)b * DIM_;
        unsigned short* zs = z + (size_t)(b + 2048) * DIM_;
#pragma unroll
        for (int i = 0; i < 4; ++i) {
            const float* tx = (const float*)&tv[i];
            const float* sx = (const float*)&sv[i];
            ushort4 pt = make_ushort4(f2bf(tx[0] * rinvT), f2bf(tx[1] * rinvT),
                                      f2bf(tx[2] * rinvT), f2bf(tx[3] * rinvT));
            ushort4 ps = make_ushort4(f2bf(sx[0] * rinvS), f2bf(sx[1] * rinvS),
                                      f2bf(sx[2] * rinvS), f2bf(sx[3] * rinvS));
            *(ushort4*)(zt + 4 * (tid + 256 * i)) = pt;
            *(ushort4*)(zs + 4 * (tid + 256 * i)) = ps;
        }
    }
}

// -------- Phase 2: bf16 GEMM on z. BM=128 x BN=64 tiles, upper-tri cover.
// 1056 tiles = 4.125 blocks/CU (tail 1.21x vs 1.45x at 128x128).
// LDS linear, swizzle on global source + ds_read offset: byte ^= (row&7)<<4.
__global__ __launch_bounds__(256) void cont_gemm3(
    const unsigned short* __restrict__ z,
    float* __restrict__ rowsum, float* __restrict__ pos)
{
    // XCD-aware bijective swizzle: 1056 = 8 * 132
    const int bid = blockIdx.x;
    int t = (bid & 7) * 132 + (bid >> 3);
    // t -> (bi, cj): band bi has 64 - 2*bi col-tiles starting at cj = 2*bi
    int bi = 0;
    while (t >= (64 - 2 * bi)) { t -= (64 - 2 * bi); ++bi; }
    const int cj = 2 * bi + t;
    const int brow = bi * 128, bcol = cj * 64;

    __shared__ unsigned short As[128 * 64];  // 16 KB
    __shared__ unsigned short Bs[64 * 64];   // 8 KB

    const int tid = threadIdx.x;
    const int lane = tid & 63;
    const int wid = tid >> 6;
    const int wm = wid >> 1, wn = wid & 1;   // wave -> 64-row half x 32-col half

    const int lrow = lane >> 3;  // 0..7
    const int lblk = lane & 7;   // 16B block within 128B row

    // Precompute per-lane global base offsets (element units), swizzled col.
    const unsigned short* srcA[4];
    const unsigned short* srcB[2];
#pragma unroll
    for (int i = 0; i < 4; ++i) {
        int r = wid * 32 + i * 8 + lrow;
        srcA[i] = z + (size_t)(brow + r) * DIM_ + ((lblk ^ (r & 7)) << 3);
    }
#pragma unroll
    for (int i = 0; i < 2; ++i) {
        int r = wid * 16 + i * 8 + lrow;
        srcB[i] = z + (size_t)(bcol + r) * DIM_ + ((lblk ^ (r & 7)) << 3);
    }

    f32x4 acc[4][2] = {};

    for (int kt = 0; kt < DIM_; kt += 64) {
        __syncthreads();
#pragma unroll
        for (int i = 0; i < 4; ++i) {
            unsigned short* dstA = As + (wid * 32 + i * 8) * 64;  // wave-uniform
            __builtin_amdgcn_global_load_lds(
                (const __attribute__((address_space(1))) unsigned int*)(srcA[i] + kt),
                (__attribute__((address_space(3))) unsigned int*)dstA, 16, 0, 0);
        }
#pragma unroll
        for (int i = 0; i < 2; ++i) {
            unsigned short* dstB = Bs + (wid * 16 + i * 8) * 64;
            __builtin_amdgcn_global_load_lds(
                (const __attribute__((address_space(1))) unsigned int*)(srcB[i] + kt),
                (__attribute__((address_space(3))) unsigned int*)dstB, 16, 0, 0);
        }
        __syncthreads();
#pragma unroll
        for (int ks = 0; ks < 2; ++ks) {
            bf16x8 af[4], bfr[2];
            const int li = lane & 15;
            const int kb = ks * 64 + (lane >> 4) * 16;  // byte offset within row
#pragma unroll
            for (int m = 0; m < 4; ++m) {
                int r = wm * 64 + m * 16 + li;
                int off = (r * 128 + kb) ^ ((r & 7) << 4);
                af[m] = *(const bf16x8*)((const char*)As + off);
            }
#pragma unroll
            for (int n = 0; n < 2; ++n) {
                int r = wn * 32 + n * 16 + li;
                int off = (r * 128 + kb) ^ ((r & 7) << 4);
                bfr[n] = *(const bf16x8*)((const char*)Bs + off);
            }
#pragma unroll
            for (int m = 0; m < 4; ++m)
#pragma unroll
                for (int n = 0; n < 2; ++n)
                    acc[m][n] = __builtin_amdgcn_mfma_f32_16x16x32_bf16(
                        af[m], bfr[n], acc[m][n], 0, 0, 0);
        }
    }

    // -------- epilogue
    // diag-type: col tile inside row band -> square self-mirrors: row adds only
    const bool dg   = (cj >> 1) == bi;
    const bool posT = (cj >> 1) == bi + 16;
    const int li = lane & 15;
    const int lg = lane >> 4;
    float cs[2] = {0.f, 0.f};
#pragma unroll
    for (int m = 0; m < 4; ++m) {
#pragma unroll
        for (int q = 0; q < 4; ++q) {
            int lr = wm * 64 + m * 16 + lg * 4 + q;
            int gr = brow + lr;
            float rsum = 0.f;
#pragma unroll
            for (int n = 0; n < 2; ++n) {
                int gc = bcol + wn * 32 + n * 16 + li;
                float v = acc[m][n][q];
                if (posT && gc == gr + 2048) { pos[gr] = v; pos[gc] = v; }
                float e = (dg && gr == gc) ? 0.f : __expf(2.0f * v);
                rsum += e;
                cs[n] += e;
            }
            rsum += __shfl_xor(rsum, 1);
            rsum += __shfl_xor(rsum, 2);
            rsum += __shfl_xor(rsum, 4);
            rsum += __shfl_xor(rsum, 8);
            if (li == 0) atomicAdd(&rowsum[gr], rsum);
        }
    }
    if (!dg) {
#pragma unroll
        for (int n = 0; n < 2; ++n) {
            float v = cs[n];
            v += __shfl_xor(v, 16);
            v += __shfl_xor(v, 32);
            if (lg == 0) atomicAdd(&rowsum[bcol + wn * 32 + n * 16 + li], v);
        }
    }
}

// -------- Fallback (no-ws path, verified round-1): on-the-fly normalize 128x128.
__global__ __launch_bounds__(256) void cont_gemm(
    const float* __restrict__ et, const float* __restrict__ es,
    const float* __restrict__ rinv, float* __restrict__ rowsum,
    float* __restrict__ pos)
{
    int t = blockIdx.x;
    int bi = 0;
    while (t >= (32 - bi)) { t -= (32 - bi); ++bi; }
    const int bj = bi + t;
    const int brow = bi * 128, bcol = bj * 128;

    __shared__ unsigned short As[128 * 64];
    __shared__ unsigned short Bs[128 * 64];

    const int tid = threadIdx.x;
    const int lane = tid & 63;
    const int wid = tid >> 6;
    const int wm = wid >> 1, wn = wid & 1;

    const int srow = tid >> 4;
    const int sf4 = tid & 15;

    const float* pA[8]; const float* pB[8];
    float riA[8], riB[8];
#pragma unroll
    for (int it = 0; it < 8; ++it) {
        int r = srow + it * 16;
        int ga = brow + r;
        int gb = bcol + r;
        pA[it] = (ga < 2048) ? (et + (size_t)ga * DIM_) : (es + (size_t)(ga - 2048) * DIM_);
        pB[it] = (gb < 2048) ? (et + (size_t)gb * DIM_) : (es + (size_t)(gb - 2048) * DIM_);
        riA[it] = rinv[ga]; riB[it] = rinv[gb];
    }

    f32x4 acc[4][4] = {};

    for (int kt = 0; kt < DIM_; kt += 64) {
        __syncthreads();
#pragma unroll
        for (int it = 0; it < 8; ++it) {
            int r = srow + it * 16;
            int swz = (r & 7) << 4;
            int bo = (r * 128 + sf4 * 8) ^ swz;
            {
                float4 v = *(const float4*)(pA[it] + kt + sf4 * 4);
                float ri = riA[it];
                ushort4 pk = make_ushort4(f2bf(v.x * ri), f2bf(v.y * ri),
                                          f2bf(v.z * ri), f2bf(v.w * ri));
                *(ushort4*)((char*)As + bo) = pk;
            }
            {
                float4 v = *(const float4*)(pB[it] + kt + sf4 * 4);
                float ri = riB[it];
                ushort4 pk = make_ushort4(f2bf(v.x * ri), f2bf(v.y * ri),
                                          f2bf(v.z * ri), f2bf(v.w * ri));
                *(ushort4*)((char*)Bs + bo) = pk;
            }
        }
        __syncthreads();
#pragma unroll
        for (int ks = 0; ks < 2; ++ks) {
            bf16x8 af[4], bfr[4];
            const int li = lane & 15;
            const int kb = ks * 64 + (lane >> 4) * 16;
#pragma unroll
            for (int m = 0; m < 4; ++m) {
                int r = wm * 64 + m * 16 + li;
                int off = (r * 128 + kb) ^ ((r & 7) << 4);
                af[m] = *(const bf16x8*)((const char*)As + off);
            }
#pragma unroll
            for (int n = 0; n < 4; ++n) {
                int r = wn * 64 + n * 16 + li;
                int off = (r * 128 + kb) ^ ((r & 7) << 4);
                bfr[n] = *(const bf16x8*)((const char*)Bs + off);
            }
#pragma unroll
            for (int m = 0; m < 4; ++m)
#pragma unroll
                for (int n = 0; n < 4; ++n)
                    acc[m][n] = __builtin_amdgcn_mfma_f32_16x16x32_bf16(
                        af[m], bfr[n], acc[m][n], 0, 0, 0);
        }
    }

    const bool diag = (bi == bj);
    const bool posT = (bcol == (brow ^ 2048));
    const int li = lane & 15;
    const int lg = lane >> 4;
    float cs[4] = {0.f, 0.f, 0.f, 0.f};
#pragma unroll
    for (int m = 0; m < 4; ++m) {
#pragma unroll
        for (int q = 0; q < 4; ++q) {
            int lr = wm * 64 + m * 16 + lg * 4 + q;
            float rsum = 0.f;
#pragma unroll
            for (int n = 0; n < 4; ++n) {
                int lc = wn * 64 + n * 16 + li;
                float v = acc[m][n][q];
                if (posT && lc == lr) { pos[brow + lr] = v; pos[bcol + lc] = v; }
                float e = (diag && lc == lr) ? 0.f : __expf(2.0f * v);
                rsum += e;
                cs[n] += e;
            }
            rsum += __shfl_xor(rsum, 1);
            rsum += __shfl_xor(rsum, 2);
            rsum += __shfl_xor(rsum, 4);
            rsum += __shfl_xor(rsum, 8);
            if (li == 0) atomicAdd(&rowsum[brow + lr], rsum);
        }
    }
    if (!diag) {
#pragma unroll
        for (int n = 0; n < 4; ++n) {
            float v = cs[n];
            v += __shfl_xor(v, 16);
            v += __shfl_xor(v, 32);
            if (lg == 0) atomicAdd(&rowsum[bcol + wn * 64 + n * 16 + li], v);
        }
    }
}

// -------- Phase 3: finalize scalar loss
__global__ __launch_bounds__(256) void finalize(
    const float* __restrict__ rowsum, const float* __restrict__ pos,
    const float* __restrict__ accs, float* __restrict__ out)
{
    const int tid = threadIdx.x;
    float c = 0.f;
    for (int i = tid; i < TWO_B; i += 256)
        c += logf(rowsum[i]) - 2.0f * pos[i];
    c = waveReduceSum(c);
    __shared__ float sm[4];
    if ((tid & 63) == 0) sm[tid >> 6] = c;
    __syncthreads();
    if (tid == 0) {
        float cont = (sm[0] + sm[1] + sm[2] + sm[3]) / 4096.0f;
        out[0] = cont + accs[0] / 2048.0f + accs[1] / (2048.0f * 4096.0f);
    }
}

extern "C" void kernel_launch(void* const* d_in, const int* in_sizes, int n_in,
                              void* d_out, int out_size, void* d_ws, size_t ws_size,
                              hipStream_t stream) {
    const float* et = (const float*)d_in[0];
    const float* es = (const float*)d_in[1];

    const size_t Z_BYTES = (size_t)TWO_B * DIM_ * 2;  // 32 MiB bf16
    const size_t SMALL_FLOATS = 4096 + 16 + 4096 + 4096;
    const bool fast = ws_size >= Z_BYTES + SMALL_FLOATS * sizeof(float);

    if (fast) {
        unsigned short* z = (unsigned short*)d_ws;
        float* smallf = (float*)((char*)d_ws + Z_BYTES);
        float* rowsum = smallf;
        float* accs = smallf + 4096;
        float* pos = smallf + 4096 + 16;
        float* rinv = smallf + 4096 + 16 + 4096;
        hipMemsetAsync(rowsum, 0, (4096 + 16) * sizeof(float), stream);
        hipLaunchKernelGGL(row_stats, dim3(2048), dim3(256), 0, stream, et, es, rinv, accs, z);
        hipLaunchKernelGGL(cont_gemm3, dim3(1056), dim3(256), 0, stream, z, rowsum, pos);
        hipLaunchKernelGGL(finalize, dim3(1), dim3(256), 0, stream, rowsum, pos, accs, (float*)d_out);
    } else {
        float* ws = (float*)d_ws;
        float* rowsum = ws;
        float* accs = ws + 4096;
        float* pos = ws + 4096 + 16;
        float* rinv = ws + 4096 + 16 + 4096;
        hipMemsetAsync(rowsum, 0, (4096 + 16) * sizeof(float), stream);
        hipLaunchKernelGGL(row_stats, dim3(2048), dim3(256), 0, stream, et, es, rinv, accs,
                           (unsigned short*)nullptr);
        hipLaunchKernelGGL(cont_gemm, dim3(528), dim3(256), 0, stream, et, es, rinv, rowsum, pos);
        hipLaunchKernelGGL(finalize, dim3(1), dim3(256), 0, stream, rowsum, pos, accs, (float*)d_out);
    }
}

// Round 4
// 161.581 us; speedup vs baseline: 1.8943x; 1.2447x over previous
//
#include <hip/hip_runtime.h>
#include <hip/hip_bf16.h>

#define TWO_B 4096
#define DIM_ 4096

typedef __attribute__((ext_vector_type(8))) short bf16x8;
typedef __attribute__((ext_vector_type(4))) float f32x4;

static __device__ __forceinline__ unsigned short f2bf(float x) {
    return __builtin_bit_cast(unsigned short, __float2bfloat16(x));
}

static __device__ __forceinline__ float waveReduceSum(float v) {
    v += __shfl_xor(v, 1);  v += __shfl_xor(v, 2);  v += __shfl_xor(v, 4);
    v += __shfl_xor(v, 8);  v += __shfl_xor(v, 16); v += __shfl_xor(v, 32);
    return v;
}
static __device__ __forceinline__ float waveReduceMax(float v) {
    v = fmaxf(v, __shfl_xor(v, 1));  v = fmaxf(v, __shfl_xor(v, 2));
    v = fmaxf(v, __shfl_xor(v, 4));  v = fmaxf(v, __shfl_xor(v, 8));
    v = fmaxf(v, __shfl_xor(v, 16)); v = fmaxf(v, __shfl_xor(v, 32));
    return v;
}

// -------- Phase 1: per-row stats (KD, MSE, norms) + z (bf16) write.
// No global atomics: per-block partials to kdp/msep.
__global__ __launch_bounds__(256) void row_stats(
    const float* __restrict__ et, const float* __restrict__ es,
    float* __restrict__ rinv, float* __restrict__ kdp, float* __restrict__ msep,
    unsigned short* __restrict__ z)
{
    const int b = blockIdx.x;
    const int tid = threadIdx.x;
    const int wid = tid >> 6;

    const float4* tp = (const float4*)(et + (size_t)b * DIM_);
    const float4* sp = (const float4*)(es + (size_t)b * DIM_);
    float4 tv[4], sv[4];
#pragma unroll
    for (int i = 0; i < 4; ++i) { tv[i] = tp[tid + 256 * i]; sv[i] = sp[tid + 256 * i]; }

    float mt = -1e30f, ms = -1e30f, nt2 = 0.f, ns2 = 0.f, msev = 0.f;
#pragma unroll
    for (int i = 0; i < 4; ++i) {
        const float* tx = (const float*)&tv[i];
        const float* sx = (const float*)&sv[i];
#pragma unroll
        for (int j = 0; j < 4; ++j) {
            float a = tx[j], c = sx[j];
            mt = fmaxf(mt, a); ms = fmaxf(ms, c);
            nt2 += a * a; ns2 += c * c;
            float d = c - a; msev += d * d;
        }
    }
    mt = waveReduceMax(mt); ms = waveReduceMax(ms);
    __shared__ float smx[4], sms[4];
    if ((tid & 63) == 0) { smx[wid] = mt; sms[wid] = ms; }
    __syncthreads();
    mt = fmaxf(fmaxf(smx[0], smx[1]), fmaxf(smx[2], smx[3]));
    ms = fmaxf(fmaxf(sms[0], sms[1]), fmaxf(sms[2], sms[3]));

    float se_t = 0.f, st = 0.f, sx_ = 0.f, se_s = 0.f;
#pragma unroll
    for (int i = 0; i < 4; ++i) {
        const float* tx = (const float*)&tv[i];
        const float* sx = (const float*)&sv[i];
#pragma unroll
        for (int j = 0; j < 4; ++j) {
            float a = tx[j], c = sx[j];
            float e = __expf(a - mt);
            se_t += e; st += e * a; sx_ += e * c;
            se_s += __expf(c - ms);
        }
    }
    float v0 = waveReduceSum(se_t), v1 = waveReduceSum(st), v2 = waveReduceSum(sx_);
    float v3 = waveReduceSum(se_s), v4 = waveReduceSum(nt2), v5 = waveReduceSum(ns2);
    float v6 = waveReduceSum(msev);
    __shared__ float sred[7][4];
    if ((tid & 63) == 0) {
        sred[0][wid] = v0; sred[1][wid] = v1; sred[2][wid] = v2; sred[3][wid] = v3;
        sred[4][wid] = v4; sred[5][wid] = v5; sred[6][wid] = v6;
    }
    __syncthreads();
    const float rT = sred[4][0] + sred[4][1] + sred[4][2] + sred[4][3];
    const float rS = sred[5][0] + sred[5][1] + sred[5][2] + sred[5][3];
    const float rinvT = 1.f / fmaxf(sqrtf(rT), 1e-8f);
    const float rinvS = 1.f / fmaxf(sqrtf(rS), 1e-8f);

    if (tid == 0) {
        float r0 = sred[0][0] + sred[0][1] + sred[0][2] + sred[0][3];
        float r1 = sred[1][0] + sred[1][1] + sred[1][2] + sred[1][3];
        float r2 = sred[2][0] + sred[2][1] + sred[2][2] + sred[2][3];
        float r3 = sred[3][0] + sred[3][1] + sred[3][2] + sred[3][3];
        float r6 = sred[6][0] + sred[6][1] + sred[6][2] + sred[6][3];
        float lse_t = mt + logf(r0);
        float lse_s = ms + logf(r3);
        kdp[b]  = (r1 - r2) / r0 - lse_t + lse_s;
        msep[b] = r6;
        rinv[b]        = rinvT;
        rinv[b + 2048] = rinvS;
    }

    if (z) {
        unsigned short* zt = z + (size_t)b * DIM_;
        unsigned short* zs = z + (size_t)(b + 2048) * DIM_;
#pragma unroll
        for (int i = 0; i < 4; ++i) {
            const float* tx = (const float*)&tv[i];
            const float* sx = (const float*)&sv[i];
            ushort4 pt = make_ushort4(f2bf(tx[0] * rinvT), f2bf(tx[1] * rinvT),
                                      f2bf(tx[2] * rinvT), f2bf(tx[3] * rinvT));
            ushort4 ps = make_ushort4(f2bf(sx[0] * rinvS), f2bf(sx[1] * rinvS),
                                      f2bf(sx[2] * rinvS), f2bf(sx[3] * rinvS));
            *(ushort4*)(zt + 4 * (tid + 256 * i)) = pt;
            *(ushort4*)(zs + 4 * (tid + 256 * i)) = ps;
        }
    }
}

// -------- Phase 2: bf16 GEMM on z. BM=128 x BN=64 upper-tri tiles.
// 2-phase double-buffered pipeline: STAGE(next) issued BEFORE compute(cur);
// one vmcnt(0)+barrier per K-step. LDS 48KB, swizzle byte^=(row&7)<<4 applied
// on global source + ds_read offset (same involution), linear gload_lds dest.
__global__ __launch_bounds__(256) void cont_gemm4(
    const unsigned short* __restrict__ z,
    float* __restrict__ rowsum, float* __restrict__ pos)
{
    // XCD-aware bijective swizzle: 1056 = 8 * 132
    const int bid = blockIdx.x;
    int t = (bid & 7) * 132 + (bid >> 3);
    int bi = 0;
    while (t >= (64 - 2 * bi)) { t -= (64 - 2 * bi); ++bi; }
    const int cj = 2 * bi + t;
    const int brow = bi * 128, bcol = cj * 64;

    __shared__ unsigned short As[2][128 * 64];  // 32 KB
    __shared__ unsigned short Bs[2][64 * 64];   // 16 KB

    const int tid = threadIdx.x;
    const int lane = tid & 63;
    const int wid = tid >> 6;
    const int wm = wid >> 1, wn = wid & 1;

    const int lrow = lane >> 3;  // 0..7
    const int lblk = lane & 7;   // 16B block within 128B row

    const unsigned short* srcA[4];
    const unsigned short* srcB[2];
#pragma unroll
    for (int i = 0; i < 4; ++i) {
        int r = wid * 32 + i * 8 + lrow;
        srcA[i] = z + (size_t)(brow + r) * DIM_ + ((lblk ^ (r & 7)) << 3);
    }
#pragma unroll
    for (int i = 0; i < 2; ++i) {
        int r = wid * 16 + i * 8 + lrow;
        srcB[i] = z + (size_t)(bcol + r) * DIM_ + ((lblk ^ (r & 7)) << 3);
    }

    f32x4 acc[4][2] = {};

    auto STAGE = [&](int buf, int kt) {
#pragma unroll
        for (int i = 0; i < 4; ++i) {
            unsigned short* dstA = &As[buf][(wid * 32 + i * 8) * 64];
            __builtin_amdgcn_global_load_lds(
                (const __attribute__((address_space(1))) unsigned int*)(srcA[i] + kt),
                (__attribute__((address_space(3))) unsigned int*)dstA, 16, 0, 0);
        }
#pragma unroll
        for (int i = 0; i < 2; ++i) {
            unsigned short* dstB = &Bs[buf][(wid * 16 + i * 8) * 64];
            __builtin_amdgcn_global_load_lds(
                (const __attribute__((address_space(1))) unsigned int*)(srcB[i] + kt),
                (__attribute__((address_space(3))) unsigned int*)dstB, 16, 0, 0);
        }
    };

    auto COMPUTE = [&](int buf) {
        const int li = lane & 15;
#pragma unroll
        for (int ks = 0; ks < 2; ++ks) {
            bf16x8 af[4], bfr[2];
            const int kb = ks * 64 + (lane >> 4) * 16;
#pragma unroll
            for (int m = 0; m < 4; ++m) {
                int r = wm * 64 + m * 16 + li;
                int off = (r * 128 + kb) ^ ((r & 7) << 4);
                af[m] = *(const bf16x8*)((const char*)&As[buf][0] + off);
            }
#pragma unroll
            for (int n = 0; n < 2; ++n) {
                int r = wn * 32 + n * 16 + li;
                int off = (r * 128 + kb) ^ ((r & 7) << 4);
                bfr[n] = *(const bf16x8*)((const char*)&Bs[buf][0] + off);
            }
            __builtin_amdgcn_s_setprio(1);
#pragma unroll
            for (int m = 0; m < 4; ++m)
#pragma unroll
                for (int n = 0; n < 2; ++n)
                    acc[m][n] = __builtin_amdgcn_mfma_f32_16x16x32_bf16(
                        af[m], bfr[n], acc[m][n], 0, 0, 0);
            __builtin_amdgcn_s_setprio(0);
        }
    };

    STAGE(0, 0);
    asm volatile("s_waitcnt vmcnt(0)" ::: "memory");
    __builtin_amdgcn_s_barrier();

    for (int kt = 0; kt < DIM_; kt += 128) {
        STAGE(1, kt + 64);                        // always valid: kt+64 <= 4032
        COMPUTE(0);
        asm volatile("s_waitcnt vmcnt(0)" ::: "memory");
        __builtin_amdgcn_s_barrier();
        if (kt + 128 < DIM_) STAGE(0, kt + 128);
        COMPUTE(1);
        asm volatile("s_waitcnt vmcnt(0)" ::: "memory");
        __builtin_amdgcn_s_barrier();
    }

    // -------- epilogue
    const bool dg   = (cj >> 1) == bi;        // col tile inside diagonal band
    const bool posT = (cj >> 1) == bi + 16;   // positives band
    const int li = lane & 15;
    const int lg = lane >> 4;
    float cs[2] = {0.f, 0.f};
#pragma unroll
    for (int m = 0; m < 4; ++m) {
#pragma unroll
        for (int q = 0; q < 4; ++q) {
            int lr = wm * 64 + m * 16 + lg * 4 + q;
            int gr = brow + lr;
            float rsum = 0.f;
#pragma unroll
            for (int n = 0; n < 2; ++n) {
                int gc = bcol + wn * 32 + n * 16 + li;
                float v = acc[m][n][q];
                if (posT && gc == gr + 2048) { pos[gr] = v; pos[gc] = v; }
                float e = (dg && gr == gc) ? 0.f : __expf(2.0f * v);
                rsum += e;
                cs[n] += e;
            }
            rsum += __shfl_xor(rsum, 1);
            rsum += __shfl_xor(rsum, 2);
            rsum += __shfl_xor(rsum, 4);
            rsum += __shfl_xor(rsum, 8);
            if (li == 0) atomicAdd(&rowsum[gr], rsum);
        }
    }
    if (!dg) {
#pragma unroll
        for (int n = 0; n < 2; ++n) {
            float v = cs[n];
            v += __shfl_xor(v, 16);
            v += __shfl_xor(v, 32);
            if (lg == 0) atomicAdd(&rowsum[bcol + wn * 32 + n * 16 + li], v);
        }
    }
}

// -------- Fallback (no-ws path): on-the-fly normalize 128x128, single-buffer.
__global__ __launch_bounds__(256) void cont_gemm(
    const float* __restrict__ et, const float* __restrict__ es,
    const float* __restrict__ rinv, float* __restrict__ rowsum,
    float* __restrict__ pos)
{
    int t = blockIdx.x;
    int bi = 0;
    while (t >= (32 - bi)) { t -= (32 - bi); ++bi; }
    const int bj = bi + t;
    const int brow = bi * 128, bcol = bj * 128;

    __shared__ unsigned short As[128 * 64];
    __shared__ unsigned short Bs[128 * 64];

    const int tid = threadIdx.x;
    const int lane = tid & 63;
    const int wid = tid >> 6;
    const int wm = wid >> 1, wn = wid & 1;

    const int srow = tid >> 4;
    const int sf4 = tid & 15;

    const float* pA[8]; const float* pB[8];
    float riA[8], riB[8];
#pragma unroll
    for (int it = 0; it < 8; ++it) {
        int r = srow + it * 16;
        int ga = brow + r;
        int gb = bcol + r;
        pA[it] = (ga < 2048) ? (et + (size_t)ga * DIM_) : (es + (size_t)(ga - 2048) * DIM_);
        pB[it] = (gb < 2048) ? (et + (size_t)gb * DIM_) : (es + (size_t)(gb - 2048) * DIM_);
        riA[it] = rinv[ga]; riB[it] = rinv[gb];
    }

    f32x4 acc[4][4] = {};

    for (int kt = 0; kt < DIM_; kt += 64) {
        __syncthreads();
#pragma unroll
        for (int it = 0; it < 8; ++it) {
            int r = srow + it * 16;
            int swz = (r & 7) << 4;
            int bo = (r * 128 + sf4 * 8) ^ swz;
            {
                float4 v = *(const float4*)(pA[it] + kt + sf4 * 4);
                float ri = riA[it];
                ushort4 pk = make_ushort4(f2bf(v.x * ri), f2bf(v.y * ri),
                                          f2bf(v.z * ri), f2bf(v.w * ri));
                *(ushort4*)((char*)As + bo) = pk;
            }
            {
                float4 v = *(const float4*)(pB[it] + kt + sf4 * 4);
                float ri = riB[it];
                ushort4 pk = make_ushort4(f2bf(v.x * ri), f2bf(v.y * ri),
                                          f2bf(v.z * ri), f2bf(v.w * ri));
                *(ushort4*)((char*)Bs + bo) = pk;
            }
        }
        __syncthreads();
#pragma unroll
        for (int ks = 0; ks < 2; ++ks) {
            bf16x8 af[4], bfr[4];
            const int li = lane & 15;
            const int kb = ks * 64 + (lane >> 4) * 16;
#pragma unroll
            for (int m = 0; m < 4; ++m) {
                int r = wm * 64 + m * 16 + li;
                int off = (r * 128 + kb) ^ ((r & 7) << 4);
                af[m] = *(const bf16x8*)((const char*)As + off);
            }
#pragma unroll
            for (int n = 0; n < 4; ++n) {
                int r = wn * 64 + n * 16 + li;
                int off = (r * 128 + kb) ^ ((r & 7) << 4);
                bfr[n] = *(const bf16x8*)((const char*)Bs + off);
            }
#pragma unroll
            for (int m = 0; m < 4; ++m)
#pragma unroll
                for (int n = 0; n < 4; ++n)
                    acc[m][n] = __builtin_amdgcn_mfma_f32_16x16x32_bf16(
                        af[m], bfr[n], acc[m][n], 0, 0, 0);
        }
    }

    const bool diag = (bi == bj);
    const bool posT = (bcol == (brow ^ 2048));
    const int li = lane & 15;
    const int lg = lane >> 4;
    float cs[4] = {0.f, 0.f, 0.f, 0.f};
#pragma unroll
    for (int m = 0; m < 4; ++m) {
#pragma unroll
        for (int q = 0; q < 4; ++q) {
            int lr = wm * 64 + m * 16 + lg * 4 + q;
            float rsum = 0.f;
#pragma unroll
            for (int n = 0; n < 4; ++n) {
                int lc = wn * 64 + n * 16 + li;
                float v = acc[m][n][q];
                if (posT && lc == lr) { pos[brow + lr] = v; pos[bcol + lc] = v; }
                float e = (diag && lc == lr) ? 0.f : __expf(2.0f * v);
                rsum += e;
                cs[n] += e;
            }
            rsum += __shfl_xor(rsum, 1);
            rsum += __shfl_xor(rsum, 2);
            rsum += __shfl_xor(rsum, 4);
            rsum += __shfl_xor(rsum, 8);
            if (li == 0) atomicAdd(&rowsum[brow + lr], rsum);
        }
    }
    if (!diag) {
#pragma unroll
        for (int n = 0; n < 4; ++n) {
            float v = cs[n];
            v += __shfl_xor(v, 16);
            v += __shfl_xor(v, 32);
            if (lg == 0) atomicAdd(&rowsum[bcol + wn * 64 + n * 16 + li], v);
        }
    }
}

// -------- Phase 3: finalize scalar loss (also reduces kd/mse partials)
__global__ __launch_bounds__(256) void finalize(
    const float* __restrict__ rowsum, const float* __restrict__ pos,
    const float* __restrict__ kdp, const float* __restrict__ msep,
    float* __restrict__ out)
{
    const int tid = threadIdx.x;
    float c = 0.f;
    for (int i = tid; i < TWO_B; i += 256)
        c += logf(rowsum[i]) - 2.0f * pos[i];
    float kd = 0.f, ms = 0.f;
    for (int i = tid; i < 2048; i += 256) { kd += kdp[i]; ms += msep[i]; }
    c = waveReduceSum(c); kd = waveReduceSum(kd); ms = waveReduceSum(ms);
    __shared__ float sm[3][4];
    if ((tid & 63) == 0) { sm[0][tid >> 6] = c; sm[1][tid >> 6] = kd; sm[2][tid >> 6] = ms; }
    __syncthreads();
    if (tid == 0) {
        float cont = (sm[0][0] + sm[0][1] + sm[0][2] + sm[0][3]) / 4096.0f;
        float kds  = (sm[1][0] + sm[1][1] + sm[1][2] + sm[1][3]) / 2048.0f;
        float mses = (sm[2][0] + sm[2][1] + sm[2][2] + sm[2][3]) / (2048.0f * 4096.0f);
        out[0] = cont + kds + mses;
    }
}

extern "C" void kernel_launch(void* const* d_in, const int* in_sizes, int n_in,
                              void* d_out, int out_size, void* d_ws, size_t ws_size,
                              hipStream_t stream) {
    const float* et = (const float*)d_in[0];
    const float* es = (const float*)d_in[1];

    const size_t Z_BYTES = (size_t)TWO_B * DIM_ * 2;  // 32 MiB bf16
    const size_t SMALL_FLOATS = 4096 * 3 + 2048 * 2;
    const bool fast = ws_size >= Z_BYTES + SMALL_FLOATS * sizeof(float);

    if (fast) {
        unsigned short* z = (unsigned short*)d_ws;
        float* smallf = (float*)((char*)d_ws + Z_BYTES);
        float* rowsum = smallf;
        float* pos  = smallf + 4096;
        float* rinv = smallf + 4096 * 2;
        float* kdp  = smallf + 4096 * 3;
        float* msep = smallf + 4096 * 3 + 2048;
        hipMemsetAsync(rowsum, 0, 4096 * sizeof(float), stream);
        hipLaunchKernelGGL(row_stats, dim3(2048), dim3(256), 0, stream, et, es, rinv, kdp, msep, z);
        hipLaunchKernelGGL(cont_gemm4, dim3(1056), dim3(256), 0, stream, z, rowsum, pos);
        hipLaunchKernelGGL(finalize, dim3(1), dim3(256), 0, stream, rowsum, pos, kdp, msep, (float*)d_out);
    } else {
        float* ws = (float*)d_ws;
        float* rowsum = ws;
        float* pos  = ws + 4096;
        float* rinv = ws + 4096 * 2;
        float* kdp  = ws + 4096 * 3;
        float* msep = ws + 4096 * 3 + 2048;
        hipMemsetAsync(rowsum, 0, 4096 * sizeof(float), stream);
        hipLaunchKernelGGL(row_stats, dim3(2048), dim3(256), 0, stream, et, es, rinv, kdp, msep,
                           (unsigned short*)nullptr);
        hipLaunchKernelGGL(cont_gemm, dim3(528), dim3(256), 0, stream, et, es, rinv, rowsum, pos);
        hipLaunchKernelGGL(finalize, dim3(1), dim3(256), 0, stream, rowsum, pos, kdp, msep, (float*)d_out);
    }
}

// Round 5
// 129.859 us; speedup vs baseline: 2.3571x; 1.2443x over previous
//
#include <hip/hip_runtime.h>
#include <hip/hip_bf16.h>

#define TWO_B 4096
#define DIM_ 4096

typedef __attribute__((ext_vector_type(8))) short bf16x8;
typedef __attribute__((ext_vector_type(4))) float f32x4;

static __device__ __forceinline__ unsigned short f2bf(float x) {
    return __builtin_bit_cast(unsigned short, __float2bfloat16(x));
}

static __device__ __forceinline__ float waveReduceSum(float v) {
    v += __shfl_xor(v, 1);  v += __shfl_xor(v, 2);  v += __shfl_xor(v, 4);
    v += __shfl_xor(v, 8);  v += __shfl_xor(v, 16); v += __shfl_xor(v, 32);
    return v;
}
static __device__ __forceinline__ float waveReduceMax(float v) {
    v = fmaxf(v, __shfl_xor(v, 1));  v = fmaxf(v, __shfl_xor(v, 2));
    v = fmaxf(v, __shfl_xor(v, 4));  v = fmaxf(v, __shfl_xor(v, 8));
    v = fmaxf(v, __shfl_xor(v, 16)); v = fmaxf(v, __shfl_xor(v, 32));
    return v;
}

// -------- Phase 1: per-row stats (KD, MSE, norms) + z (bf16) write.
__global__ __launch_bounds__(256) void row_stats(
    const float* __restrict__ et, const float* __restrict__ es,
    float* __restrict__ rinv, float* __restrict__ kdp, float* __restrict__ msep,
    unsigned short* __restrict__ z)
{
    const int b = blockIdx.x;
    const int tid = threadIdx.x;
    const int wid = tid >> 6;

    const float4* tp = (const float4*)(et + (size_t)b * DIM_);
    const float4* sp = (const float4*)(es + (size_t)b * DIM_);
    float4 tv[4], sv[4];
#pragma unroll
    for (int i = 0; i < 4; ++i) { tv[i] = tp[tid + 256 * i]; sv[i] = sp[tid + 256 * i]; }

    float mt = -1e30f, ms = -1e30f, nt2 = 0.f, ns2 = 0.f, msev = 0.f;
#pragma unroll
    for (int i = 0; i < 4; ++i) {
        const float* tx = (const float*)&tv[i];
        const float* sx = (const float*)&sv[i];
#pragma unroll
        for (int j = 0; j < 4; ++j) {
            float a = tx[j], c = sx[j];
            mt = fmaxf(mt, a); ms = fmaxf(ms, c);
            nt2 += a * a; ns2 += c * c;
            float d = c - a; msev += d * d;
        }
    }
    mt = waveReduceMax(mt); ms = waveReduceMax(ms);
    __shared__ float smx[4], sms[4];
    if ((tid & 63) == 0) { smx[wid] = mt; sms[wid] = ms; }
    __syncthreads();
    mt = fmaxf(fmaxf(smx[0], smx[1]), fmaxf(smx[2], smx[3]));
    ms = fmaxf(fmaxf(sms[0], sms[1]), fmaxf(sms[2], sms[3]));

    float se_t = 0.f, st = 0.f, sx_ = 0.f, se_s = 0.f;
#pragma unroll
    for (int i = 0; i < 4; ++i) {
        const float* tx = (const float*)&tv[i];
        const float* sx = (const float*)&sv[i];
#pragma unroll
        for (int j = 0; j < 4; ++j) {
            float a = tx[j], c = sx[j];
            float e = __expf(a - mt);
            se_t += e; st += e * a; sx_ += e * c;
            se_s += __expf(c - ms);
        }
    }
    float v0 = waveReduceSum(se_t), v1 = waveReduceSum(st), v2 = waveReduceSum(sx_);
    float v3 = waveReduceSum(se_s), v4 = waveReduceSum(nt2), v5 = waveReduceSum(ns2);
    float v6 = waveReduceSum(msev);
    __shared__ float sred[7][4];
    if ((tid & 63) == 0) {
        sred[0][wid] = v0; sred[1][wid] = v1; sred[2][wid] = v2; sred[3][wid] = v3;
        sred[4][wid] = v4; sred[5][wid] = v5; sred[6][wid] = v6;
    }
    __syncthreads();
    const float rT = sred[4][0] + sred[4][1] + sred[4][2] + sred[4][3];
    const float rS = sred[5][0] + sred[5][1] + sred[5][2] + sred[5][3];
    const float rinvT = 1.f / fmaxf(sqrtf(rT), 1e-8f);
    const float rinvS = 1.f / fmaxf(sqrtf(rS), 1e-8f);

    if (tid == 0) {
        float r0 = sred[0][0] + sred[0][1] + sred[0][2] + sred[0][3];
        float r1 = sred[1][0] + sred[1][1] + sred[1][2] + sred[1][3];
        float r2 = sred[2][0] + sred[2][1] + sred[2][2] + sred[2][3];
        float r3 = sred[3][0] + sred[3][1] + sred[3][2] + sred[3][3];
        float r6 = sred[6][0] + sred[6][1] + sred[6][2] + sred[6][3];
        float lse_t = mt + logf(r0);
        float lse_s = ms + logf(r3);
        kdp[b]  = (r1 - r2) / r0 - lse_t + lse_s;
        msep[b] = r6;
        rinv[b]        = rinvT;
        rinv[b + 2048] = rinvS;
    }

    if (z) {
        unsigned short* zt = z + (size_t)b * DIM_;
        unsigned short* zs = z + (size_t)(b + 2048) * DIM_;
#pragma unroll
        for (int i = 0; i < 4; ++i) {
            const float* tx = (const float*)&tv[i];
            const float* sx = (const float*)&sv[i];
            ushort4 pt = make_ushort4(f2bf(tx[0] * rinvT), f2bf(tx[1] * rinvT),
                                      f2bf(tx[2] * rinvT), f2bf(tx[3] * rinvT));
            ushort4 ps = make_ushort4(f2bf(sx[0] * rinvS), f2bf(sx[1] * rinvS),
                                      f2bf(sx[2] * rinvS), f2bf(sx[3] * rinvS));
            *(ushort4*)(zt + 4 * (tid + 256 * i)) = pt;
            *(ushort4*)(zs + 4 * (tid + 256 * i)) = ps;
        }
    }
}

// -------- Phase 2: bf16 GEMM on z. BM=128 x BN=64 upper-tri tiles (1056 blk,
// 4.1/CU balance) with TWO waves of 128 threads, each wave owning the full
// 64x64 half (m97 per-wave density: 8 ds_read_b128 : 16 MFMA per ks).
// LDS 24KB -> ~6 blocks/CU capacity -> all resident. Single-buffered (round-4
// showed dbuf null). Swizzle byte^=(row&7)<<4 on global source + ds_read.
__global__ __launch_bounds__(128, 3) void cont_gemm5(
    const unsigned short* __restrict__ z,
    float* __restrict__ rowsum, float* __restrict__ pos)
{
    // XCD-aware bijective swizzle: 1056 = 8 * 132
    const int bid = blockIdx.x;
    int t = (bid & 7) * 132 + (bid >> 3);
    int bi = 0;
    while (t >= (64 - 2 * bi)) { t -= (64 - 2 * bi); ++bi; }
    const int cj = 2 * bi + t;
    const int brow = bi * 128, bcol = cj * 64;

    __shared__ unsigned short As[128 * 64];  // 16 KB
    __shared__ unsigned short Bs[64 * 64];   // 8 KB

    const int tid = threadIdx.x;
    const int lane = tid & 63;
    const int w = tid >> 6;       // wave id 0..1 -> row half
    const int lrow = lane >> 3;   // 0..7
    const int lblk = lane & 7;    // 16B block within 128B row

    // r&7 == lrow for every staged row -> single swizzled base per operand
    const unsigned short* baseA =
        z + (size_t)(brow + w * 64 + lrow) * DIM_ + ((lblk ^ lrow) << 3);
    const unsigned short* baseB =
        z + (size_t)(bcol + w * 32 + lrow) * DIM_ + ((lblk ^ lrow) << 3);

    f32x4 acc[4][4] = {};

    for (int kt = 0; kt < DIM_; kt += 64) {
        __syncthreads();
#pragma unroll
        for (int i = 0; i < 8; ++i) {   // A: 64 rows per wave, 8 rows per issue
            unsigned short* dstA = As + (w * 64 + i * 8) * 64;
            __builtin_amdgcn_global_load_lds(
                (const __attribute__((address_space(1))) unsigned int*)
                    (baseA + (size_t)i * 8 * DIM_ + kt),
                (__attribute__((address_space(3))) unsigned int*)dstA, 16, 0, 0);
        }
#pragma unroll
        for (int i = 0; i < 4; ++i) {   // B: 32 rows per wave
            unsigned short* dstB = Bs + (w * 32 + i * 8) * 64;
            __builtin_amdgcn_global_load_lds(
                (const __attribute__((address_space(1))) unsigned int*)
                    (baseB + (size_t)i * 8 * DIM_ + kt),
                (__attribute__((address_space(3))) unsigned int*)dstB, 16, 0, 0);
        }
        __syncthreads();
#pragma unroll
        for (int ks = 0; ks < 2; ++ks) {
            bf16x8 af[4], bfr[4];
            const int li = lane & 15;
            const int kb = ks * 64 + (lane >> 4) * 16;  // byte offset within row
#pragma unroll
            for (int m = 0; m < 4; ++m) {
                int r = w * 64 + m * 16 + li;
                int off = (r * 128 + kb) ^ ((r & 7) << 4);
                af[m] = *(const bf16x8*)((const char*)As + off);
            }
#pragma unroll
            for (int n = 0; n < 4; ++n) {
                int r = n * 16 + li;
                int off = (r * 128 + kb) ^ ((r & 7) << 4);
                bfr[n] = *(const bf16x8*)((const char*)Bs + off);
            }
            __builtin_amdgcn_s_setprio(1);
#pragma unroll
            for (int m = 0; m < 4; ++m)
#pragma unroll
                for (int n = 0; n < 4; ++n)
                    acc[m][n] = __builtin_amdgcn_mfma_f32_16x16x32_bf16(
                        af[m], bfr[n], acc[m][n], 0, 0, 0);
            __builtin_amdgcn_s_setprio(0);
        }
    }

    // -------- epilogue
    const bool dg   = (cj >> 1) == bi;        // col tile inside diagonal band
    const bool posT = (cj >> 1) == bi + 16;   // positives band
    const int li = lane & 15;
    const int lg = lane >> 4;
    float cs[4] = {0.f, 0.f, 0.f, 0.f};
#pragma unroll
    for (int m = 0; m < 4; ++m) {
#pragma unroll
        for (int q = 0; q < 4; ++q) {
            int lr = w * 64 + m * 16 + lg * 4 + q;
            int gr = brow + lr;
            float rsum = 0.f;
#pragma unroll
            for (int n = 0; n < 4; ++n) {
                int gc = bcol + n * 16 + li;
                float v = acc[m][n][q];
                if (posT && gc == gr + 2048) { pos[gr] = v; pos[gc] = v; }
                float e = (dg && gr == gc) ? 0.f : __expf(2.0f * v);
                rsum += e;
                cs[n] += e;
            }
            rsum += __shfl_xor(rsum, 1);
            rsum += __shfl_xor(rsum, 2);
            rsum += __shfl_xor(rsum, 4);
            rsum += __shfl_xor(rsum, 8);
            if (li == 0) atomicAdd(&rowsum[gr], rsum);
        }
    }
    if (!dg) {
#pragma unroll
        for (int n = 0; n < 4; ++n) {
            float v = cs[n];
            v += __shfl_xor(v, 16);
            v += __shfl_xor(v, 32);
            if (lg == 0) atomicAdd(&rowsum[bcol + n * 16 + li], v);
        }
    }
}

// -------- Fallback (no-ws path): on-the-fly normalize 128x128, single-buffer.
__global__ __launch_bounds__(256) void cont_gemm(
    const float* __restrict__ et, const float* __restrict__ es,
    const float* __restrict__ rinv, float* __restrict__ rowsum,
    float* __restrict__ pos)
{
    int t = blockIdx.x;
    int bi = 0;
    while (t >= (32 - bi)) { t -= (32 - bi); ++bi; }
    const int bj = bi + t;
    const int brow = bi * 128, bcol = bj * 128;

    __shared__ unsigned short As[128 * 64];
    __shared__ unsigned short Bs[128 * 64];

    const int tid = threadIdx.x;
    const int lane = tid & 63;
    const int wid = tid >> 6;
    const int wm = wid >> 1, wn = wid & 1;

    const int srow = tid >> 4;
    const int sf4 = tid & 15;

    const float* pA[8]; const float* pB[8];
    float riA[8], riB[8];
#pragma unroll
    for (int it = 0; it < 8; ++it) {
        int r = srow + it * 16;
        int ga = brow + r;
        int gb = bcol + r;
        pA[it] = (ga < 2048) ? (et + (size_t)ga * DIM_) : (es + (size_t)(ga - 2048) * DIM_);
        pB[it] = (gb < 2048) ? (et + (size_t)gb * DIM_) : (es + (size_t)(gb - 2048) * DIM_);
        riA[it] = rinv[ga]; riB[it] = rinv[gb];
    }

    f32x4 acc[4][4] = {};

    for (int kt = 0; kt < DIM_; kt += 64) {
        __syncthreads();
#pragma unroll
        for (int it = 0; it < 8; ++it) {
            int r = srow + it * 16;
            int swz = (r & 7) << 4;
            int bo = (r * 128 + sf4 * 8) ^ swz;
            {
                float4 v = *(const float4*)(pA[it] + kt + sf4 * 4);
                float ri = riA[it];
                ushort4 pk = make_ushort4(f2bf(v.x * ri), f2bf(v.y * ri),
                                          f2bf(v.z * ri), f2bf(v.w * ri));
                *(ushort4*)((char*)As + bo) = pk;
            }
            {
                float4 v = *(const float4*)(pB[it] + kt + sf4 * 4);
                float ri = riB[it];
                ushort4 pk = make_ushort4(f2bf(v.x * ri), f2bf(v.y * ri),
                                          f2bf(v.z * ri), f2bf(v.w * ri));
                *(ushort4*)((char*)Bs + bo) = pk;
            }
        }
        __syncthreads();
#pragma unroll
        for (int ks = 0; ks < 2; ++ks) {
            bf16x8 af[4], bfr[4];
            const int li = lane & 15;
            const int kb = ks * 64 + (lane >> 4) * 16;
#pragma unroll
            for (int m = 0; m < 4; ++m) {
                int r = wm * 64 + m * 16 + li;
                int off = (r * 128 + kb) ^ ((r & 7) << 4);
                af[m] = *(const bf16x8*)((const char*)As + off);
            }
#pragma unroll
            for (int n = 0; n < 4; ++n) {
                int r = wn * 64 + n * 16 + li;
                int off = (r * 128 + kb) ^ ((r & 7) << 4);
                bfr[n] = *(const bf16x8*)((const char*)Bs + off);
            }
#pragma unroll
            for (int m = 0; m < 4; ++m)
#pragma unroll
                for (int n = 0; n < 4; ++n)
                    acc[m][n] = __builtin_amdgcn_mfma_f32_16x16x32_bf16(
                        af[m], bfr[n], acc[m][n], 0, 0, 0);
        }
    }

    const bool diag = (bi == bj);
    const bool posT = (bcol == (brow ^ 2048));
    const int li = lane & 15;
    const int lg = lane >> 4;
    float cs[4] = {0.f, 0.f, 0.f, 0.f};
#pragma unroll
    for (int m = 0; m < 4; ++m) {
#pragma unroll
        for (int q = 0; q < 4; ++q) {
            int lr = wm * 64 + m * 16 + lg * 4 + q;
            float rsum = 0.f;
#pragma unroll
            for (int n = 0; n < 4; ++n) {
                int lc = wn * 64 + n * 16 + li;
                float v = acc[m][n][q];
                if (posT && lc == lr) { pos[brow + lr] = v; pos[bcol + lc] = v; }
                float e = (diag && lc == lr) ? 0.f : __expf(2.0f * v);
                rsum += e;
                cs[n] += e;
            }
            rsum += __shfl_xor(rsum, 1);
            rsum += __shfl_xor(rsum, 2);
            rsum += __shfl_xor(rsum, 4);
            rsum += __shfl_xor(rsum, 8);
            if (li == 0) atomicAdd(&rowsum[brow + lr], rsum);
        }
    }
    if (!diag) {
#pragma unroll
        for (int n = 0; n < 4; ++n) {
            float v = cs[n];
            v += __shfl_xor(v, 16);
            v += __shfl_xor(v, 32);
            if (lg == 0) atomicAdd(&rowsum[bcol + wn * 64 + n * 16 + li], v);
        }
    }
}

// -------- Phase 3: finalize scalar loss (also reduces kd/mse partials)
__global__ __launch_bounds__(256) void finalize(
    const float* __restrict__ rowsum, const float* __restrict__ pos,
    const float* __restrict__ kdp, const float* __restrict__ msep,
    float* __restrict__ out)
{
    const int tid = threadIdx.x;
    float c = 0.f;
    for (int i = tid; i < TWO_B; i += 256)
        c += logf(rowsum[i]) - 2.0f * pos[i];
    float kd = 0.f, ms = 0.f;
    for (int i = tid; i < 2048; i += 256) { kd += kdp[i]; ms += msep[i]; }
    c = waveReduceSum(c); kd = waveReduceSum(kd); ms = waveReduceSum(ms);
    __shared__ float sm[3][4];
    if ((tid & 63) == 0) { sm[0][tid >> 6] = c; sm[1][tid >> 6] = kd; sm[2][tid >> 6] = ms; }
    __syncthreads();
    if (tid == 0) {
        float cont = (sm[0][0] + sm[0][1] + sm[0][2] + sm[0][3]) / 4096.0f;
        float kds  = (sm[1][0] + sm[1][1] + sm[1][2] + sm[1][3]) / 2048.0f;
        float mses = (sm[2][0] + sm[2][1] + sm[2][2] + sm[2][3]) / (2048.0f * 4096.0f);
        out[0] = cont + kds + mses;
    }
}

extern "C" void kernel_launch(void* const* d_in, const int* in_sizes, int n_in,
                              void* d_out, int out_size, void* d_ws, size_t ws_size,
                              hipStream_t stream) {
    const float* et = (const float*)d_in[0];
    const float* es = (const float*)d_in[1];

    const size_t Z_BYTES = (size_t)TWO_B * DIM_ * 2;  // 32 MiB bf16
    const size_t SMALL_FLOATS = 4096 * 3 + 2048 * 2;
    const bool fast = ws_size >= Z_BYTES + SMALL_FLOATS * sizeof(float);

    if (fast) {
        unsigned short* z = (unsigned short*)d_ws;
        float* smallf = (float*)((char*)d_ws + Z_BYTES);
        float* rowsum = smallf;
        float* pos  = smallf + 4096;
        float* rinv = smallf + 4096 * 2;
        float* kdp  = smallf + 4096 * 3;
        float* msep = smallf + 4096 * 3 + 2048;
        hipMemsetAsync(rowsum, 0, 4096 * sizeof(float), stream);
        hipLaunchKernelGGL(row_stats, dim3(2048), dim3(256), 0, stream, et, es, rinv, kdp, msep, z);
        hipLaunchKernelGGL(cont_gemm5, dim3(1056), dim3(128), 0, stream, z, rowsum, pos);
        hipLaunchKernelGGL(finalize, dim3(1), dim3(256), 0, stream, rowsum, pos, kdp, msep, (float*)d_out);
    } else {
        float* ws = (float*)d_ws;
        float* rowsum = ws;
        float* pos  = ws + 4096;
        float* rinv = ws + 4096 * 2;
        float* kdp  = ws + 4096 * 3;
        float* msep = ws + 4096 * 3 + 2048;
        hipMemsetAsync(rowsum, 0, 4096 * sizeof(float), stream);
        hipLaunchKernelGGL(row_stats, dim3(2048), dim3(256), 0, stream, et, es, rinv, kdp, msep,
                           (unsigned short*)nullptr);
        hipLaunchKernelGGL(cont_gemm, dim3(528), dim3(256), 0, stream, et, es, rinv, rowsum, pos);
        hipLaunchKernelGGL(finalize, dim3(1), dim3(256), 0, stream, rowsum, pos, kdp, msep, (float*)d_out);
    }
}

// Round 6
// 89.247 us; speedup vs baseline: 3.4297x; 1.4550x over previous
//
#include <hip/hip_runtime.h>
#include <hip/hip_bf16.h>

#define TWO_B 4096
#define DIM_ 4096

typedef __attribute__((ext_vector_type(8))) short bf16x8;
typedef __attribute__((ext_vector_type(4))) float f32x4;
typedef __attribute__((ext_vector_type(4))) int i32x4;

static __device__ __forceinline__ unsigned short f2bf(float x) {
    return __builtin_bit_cast(unsigned short, __float2bfloat16(x));
}

static __device__ __forceinline__ float waveReduceSum(float v) {
    v += __shfl_xor(v, 1);  v += __shfl_xor(v, 2);  v += __shfl_xor(v, 4);
    v += __shfl_xor(v, 8);  v += __shfl_xor(v, 16); v += __shfl_xor(v, 32);
    return v;
}
static __device__ __forceinline__ float waveReduceMax(float v) {
    v = fmaxf(v, __shfl_xor(v, 1));  v = fmaxf(v, __shfl_xor(v, 2));
    v = fmaxf(v, __shfl_xor(v, 4));  v = fmaxf(v, __shfl_xor(v, 8));
    v = fmaxf(v, __shfl_xor(v, 16)); v = fmaxf(v, __shfl_xor(v, 32));
    return v;
}

// -------- Phase 1: per-row stats (KD, MSE, norms) + int8 z write + quant scales.
__global__ __launch_bounds__(256) void row_stats(
    const float* __restrict__ et, const float* __restrict__ es,
    float* __restrict__ rinv, float* __restrict__ qs,
    float* __restrict__ kdp, float* __restrict__ msep,
    char* __restrict__ z8)
{
    const int b = blockIdx.x;
    const int tid = threadIdx.x;
    const int wid = tid >> 6;

    const float4* tp = (const float4*)(et + (size_t)b * DIM_);
    const float4* sp = (const float4*)(es + (size_t)b * DIM_);
    float4 tv[4], sv[4];
#pragma unroll
    for (int i = 0; i < 4; ++i) { tv[i] = tp[tid + 256 * i]; sv[i] = sp[tid + 256 * i]; }

    float mt = -1e30f, ms = -1e30f, amt = 0.f, ams = 0.f;
    float nt2 = 0.f, ns2 = 0.f, msev = 0.f;
#pragma unroll
    for (int i = 0; i < 4; ++i) {
        const float* tx = (const float*)&tv[i];
        const float* sx = (const float*)&sv[i];
#pragma unroll
        for (int j = 0; j < 4; ++j) {
            float a = tx[j], c = sx[j];
            mt = fmaxf(mt, a); ms = fmaxf(ms, c);
            amt = fmaxf(amt, fabsf(a)); ams = fmaxf(ams, fabsf(c));
            nt2 += a * a; ns2 += c * c;
            float d = c - a; msev += d * d;
        }
    }
    mt = waveReduceMax(mt); ms = waveReduceMax(ms);
    amt = waveReduceMax(amt); ams = waveReduceMax(ams);
    __shared__ float smx[4], sms[4], sat[4], sas[4];
    if ((tid & 63) == 0) { smx[wid] = mt; sms[wid] = ms; sat[wid] = amt; sas[wid] = ams; }
    __syncthreads();
    mt = fmaxf(fmaxf(smx[0], smx[1]), fmaxf(smx[2], smx[3]));
    ms = fmaxf(fmaxf(sms[0], sms[1]), fmaxf(sms[2], sms[3]));
    const float maT = fmaxf(fmaxf(fmaxf(sat[0], sat[1]), fmaxf(sat[2], sat[3])), 1e-20f);
    const float maS = fmaxf(fmaxf(fmaxf(sas[0], sas[1]), fmaxf(sas[2], sas[3])), 1e-20f);

    float se_t = 0.f, st = 0.f, sx_ = 0.f, se_s = 0.f;
#pragma unroll
    for (int i = 0; i < 4; ++i) {
        const float* tx = (const float*)&tv[i];
        const float* sx = (const float*)&sv[i];
#pragma unroll
        for (int j = 0; j < 4; ++j) {
            float a = tx[j], c = sx[j];
            float e = __expf(a - mt);
            se_t += e; st += e * a; sx_ += e * c;
            se_s += __expf(c - ms);
        }
    }
    float v0 = waveReduceSum(se_t), v1 = waveReduceSum(st), v2 = waveReduceSum(sx_);
    float v3 = waveReduceSum(se_s), v4 = waveReduceSum(nt2), v5 = waveReduceSum(ns2);
    float v6 = waveReduceSum(msev);
    __shared__ float sred[7][4];
    if ((tid & 63) == 0) {
        sred[0][wid] = v0; sred[1][wid] = v1; sred[2][wid] = v2; sred[3][wid] = v3;
        sred[4][wid] = v4; sred[5][wid] = v5; sred[6][wid] = v6;
    }
    __syncthreads();
    const float rT = sred[4][0] + sred[4][1] + sred[4][2] + sred[4][3];
    const float rS = sred[5][0] + sred[5][1] + sred[5][2] + sred[5][3];
    const float rinvT = 1.f / fmaxf(sqrtf(rT), 1e-8f);
    const float rinvS = 1.f / fmaxf(sqrtf(rS), 1e-8f);

    if (tid == 0) {
        float r0 = sred[0][0] + sred[0][1] + sred[0][2] + sred[0][3];
        float r1 = sred[1][0] + sred[1][1] + sred[1][2] + sred[1][3];
        float r2 = sred[2][0] + sred[2][1] + sred[2][2] + sred[2][3];
        float r3 = sred[3][0] + sred[3][1] + sred[3][2] + sred[3][3];
        float r6 = sred[6][0] + sred[6][1] + sred[6][2] + sred[6][3];
        float lse_t = mt + logf(r0);
        float lse_s = ms + logf(r3);
        kdp[b]  = (r1 - r2) / r0 - lse_t + lse_s;
        msep[b] = r6;
        rinv[b]        = rinvT;
        rinv[b + 2048] = rinvS;
        qs[b]          = maT * rinvT * (1.f / 127.f);  // dequant scale of z row b
        qs[b + 2048]   = maS * rinvS * (1.f / 127.f);
    }

    if (z8) {
        char* zt = z8 + (size_t)b * DIM_;
        char* zs = z8 + (size_t)(b + 2048) * DIM_;
        const float fT = 127.f / maT, fS = 127.f / maS;
#pragma unroll
        for (int i = 0; i < 4; ++i) {
            const float* tx = (const float*)&tv[i];
            const float* sx = (const float*)&sv[i];
            int pt = 0, ps = 0;
#pragma unroll
            for (int j = 0; j < 4; ++j) {
                int qt = __float2int_rn(tx[j] * fT) & 0xff;
                int qv = __float2int_rn(sx[j] * fS) & 0xff;
                pt |= qt << (8 * j);
                ps |= qv << (8 * j);
            }
            ((int*)zt)[tid + 256 * i] = pt;
            ((int*)zs)[tid + 256 * i] = ps;
        }
    }
}

// -------- Phase 2: int8 GEMM on quantized z. BM=128 x BN=64 upper-tri tiles,
// BK=128 i8 (two 16x16x64 MFMAs per frag-pair) -> 32 K-steps (vs 64 bf16).
// Per-wave per-step byte profile identical to the bf16 version (128B/row).
// Swizzle byte^=(row&7)<<4 on pre-swizzled global source + ds_read offset.
__global__ __launch_bounds__(128, 3) void cont_gemm6(
    const char* __restrict__ z8, const float* __restrict__ qs,
    float* __restrict__ rowsum, float* __restrict__ pos)
{
    // XCD-aware bijective swizzle: 1056 = 8 * 132
    const int bid = blockIdx.x;
    int t = (bid & 7) * 132 + (bid >> 3);
    int bi = 0;
    while (t >= (64 - 2 * bi)) { t -= (64 - 2 * bi); ++bi; }
    const int cj = 2 * bi + t;
    const int brow = bi * 128, bcol = cj * 64;

    __shared__ char As[128 * 128];  // 16 KB: 128 rows x 128 i8
    __shared__ char Bs[64 * 128];   // 8 KB

    const int tid = threadIdx.x;
    const int lane = tid & 63;
    const int w = tid >> 6;       // wave id 0..1 -> row half
    const int lrow = lane >> 3;   // 0..7
    const int lblk = lane & 7;    // 16B block within 128B row

    const char* baseA =
        z8 + (size_t)(brow + w * 64 + lrow) * DIM_ + ((lblk ^ lrow) << 4);
    const char* baseB =
        z8 + (size_t)(bcol + w * 32 + lrow) * DIM_ + ((lblk ^ lrow) << 4);

    i32x4 acc[4][4] = {};

    for (int kt = 0; kt < DIM_; kt += 128) {
        __syncthreads();
#pragma unroll
        for (int i = 0; i < 8; ++i) {   // A: 64 rows per wave
            char* dstA = As + (w * 64 + i * 8) * 128;
            __builtin_amdgcn_global_load_lds(
                (const __attribute__((address_space(1))) unsigned int*)
                    (baseA + (size_t)i * 8 * DIM_ + kt),
                (__attribute__((address_space(3))) unsigned int*)dstA, 16, 0, 0);
        }
#pragma unroll
        for (int i = 0; i < 4; ++i) {   // B: 32 rows per wave
            char* dstB = Bs + (w * 32 + i * 8) * 128;
            __builtin_amdgcn_global_load_lds(
                (const __attribute__((address_space(1))) unsigned int*)
                    (baseB + (size_t)i * 8 * DIM_ + kt),
                (__attribute__((address_space(3))) unsigned int*)dstB, 16, 0, 0);
        }
        __syncthreads();
#pragma unroll
        for (int ks = 0; ks < 2; ++ks) {
            i32x4 af[4], bfr[4];
            const int li = lane & 15;
            const int kb = ks * 64 + (lane >> 4) * 16;  // byte offset in 128B row
#pragma unroll
            for (int m = 0; m < 4; ++m) {
                int r = w * 64 + m * 16 + li;
                int off = (r * 128 + kb) ^ ((r & 7) << 4);
                af[m] = *(const i32x4*)(As + off);
            }
#pragma unroll
            for (int n = 0; n < 4; ++n) {
                int r = n * 16 + li;
                int off = (r * 128 + kb) ^ ((r & 7) << 4);
                bfr[n] = *(const i32x4*)(Bs + off);
            }
            __builtin_amdgcn_s_setprio(1);
#pragma unroll
            for (int m = 0; m < 4; ++m)
#pragma unroll
                for (int n = 0; n < 4; ++n)
                    acc[m][n] = __builtin_amdgcn_mfma_i32_16x16x64_i8(
                        af[m], bfr[n], acc[m][n], 0, 0, 0);
            __builtin_amdgcn_s_setprio(0);
        }
    }

    // -------- epilogue: dequant, exp, diagonal mask, positives, row/col sums
    const bool dg   = (cj >> 1) == bi;        // col tile inside diagonal band
    const bool posT = (cj >> 1) == bi + 16;   // positives band
    const int li = lane & 15;
    const int lg = lane >> 4;
    float sB[4];
#pragma unroll
    for (int n = 0; n < 4; ++n) sB[n] = qs[bcol + n * 16 + li];
    float cs[4] = {0.f, 0.f, 0.f, 0.f};
#pragma unroll
    for (int m = 0; m < 4; ++m) {
#pragma unroll
        for (int q = 0; q < 4; ++q) {
            int lr = w * 64 + m * 16 + lg * 4 + q;
            int gr = brow + lr;
            float sA = qs[gr];
            float rsum = 0.f;
#pragma unroll
            for (int n = 0; n < 4; ++n) {
                int gc = bcol + n * 16 + li;
                float v = (float)acc[m][n][q] * sA * sB[n];
                if (posT && gc == gr + 2048) { pos[gr] = v; pos[gc] = v; }
                float e = (dg && gr == gc) ? 0.f : __expf(2.0f * v);
                rsum += e;
                cs[n] += e;
            }
            rsum += __shfl_xor(rsum, 1);
            rsum += __shfl_xor(rsum, 2);
            rsum += __shfl_xor(rsum, 4);
            rsum += __shfl_xor(rsum, 8);
            if (li == 0) atomicAdd(&rowsum[gr], rsum);
        }
    }
    if (!dg) {
#pragma unroll
        for (int n = 0; n < 4; ++n) {
            float v = cs[n];
            v += __shfl_xor(v, 16);
            v += __shfl_xor(v, 32);
            if (lg == 0) atomicAdd(&rowsum[bcol + n * 16 + li], v);
        }
    }
}

// -------- Fallback (no-ws path): on-the-fly normalize 128x128 bf16.
__global__ __launch_bounds__(256) void cont_gemm(
    const float* __restrict__ et, const float* __restrict__ es,
    const float* __restrict__ rinv, float* __restrict__ rowsum,
    float* __restrict__ pos)
{
    int t = blockIdx.x;
    int bi = 0;
    while (t >= (32 - bi)) { t -= (32 - bi); ++bi; }
    const int bj = bi + t;
    const int brow = bi * 128, bcol = bj * 128;

    __shared__ unsigned short As[128 * 64];
    __shared__ unsigned short Bs[128 * 64];

    const int tid = threadIdx.x;
    const int lane = tid & 63;
    const int wid = tid >> 6;
    const int wm = wid >> 1, wn = wid & 1;

    const int srow = tid >> 4;
    const int sf4 = tid & 15;

    const float* pA[8]; const float* pB[8];
    float riA[8], riB[8];
#pragma unroll
    for (int it = 0; it < 8; ++it) {
        int r = srow + it * 16;
        int ga = brow + r;
        int gb = bcol + r;
        pA[it] = (ga < 2048) ? (et + (size_t)ga * DIM_) : (es + (size_t)(ga - 2048) * DIM_);
        pB[it] = (gb < 2048) ? (et + (size_t)gb * DIM_) : (es + (size_t)(gb - 2048) * DIM_);
        riA[it] = rinv[ga]; riB[it] = rinv[gb];
    }

    f32x4 acc[4][4] = {};

    for (int kt = 0; kt < DIM_; kt += 64) {
        __syncthreads();
#pragma unroll
        for (int it = 0; it < 8; ++it) {
            int r = srow + it * 16;
            int swz = (r & 7) << 4;
            int bo = (r * 128 + sf4 * 8) ^ swz;
            {
                float4 v = *(const float4*)(pA[it] + kt + sf4 * 4);
                float ri = riA[it];
                ushort4 pk = make_ushort4(f2bf(v.x * ri), f2bf(v.y * ri),
                                          f2bf(v.z * ri), f2bf(v.w * ri));
                *(ushort4*)((char*)As + bo) = pk;
            }
            {
                float4 v = *(const float4*)(pB[it] + kt + sf4 * 4);
                float ri = riB[it];
                ushort4 pk = make_ushort4(f2bf(v.x * ri), f2bf(v.y * ri),
                                          f2bf(v.z * ri), f2bf(v.w * ri));
                *(ushort4*)((char*)Bs + bo) = pk;
            }
        }
        __syncthreads();
#pragma unroll
        for (int ks = 0; ks < 2; ++ks) {
            bf16x8 af[4], bfr[4];
            const int li = lane & 15;
            const int kb = ks * 64 + (lane >> 4) * 16;
#pragma unroll
            for (int m = 0; m < 4; ++m) {
                int r = wm * 64 + m * 16 + li;
                int off = (r * 128 + kb) ^ ((r & 7) << 4);
                af[m] = *(const bf16x8*)((const char*)As + off);
            }
#pragma unroll
            for (int n = 0; n < 4; ++n) {
                int r = wn * 64 + n * 16 + li;
                int off = (r * 128 + kb) ^ ((r & 7) << 4);
                bfr[n] = *(const bf16x8*)((const char*)Bs + off);
            }
#pragma unroll
            for (int m = 0; m < 4; ++m)
#pragma unroll
                for (int n = 0; n < 4; ++n)
                    acc[m][n] = __builtin_amdgcn_mfma_f32_16x16x32_bf16(
                        af[m], bfr[n], acc[m][n], 0, 0, 0);
        }
    }

    const bool diag = (bi == bj);
    const bool posT = (bcol == (brow ^ 2048));
    const int li = lane & 15;
    const int lg = lane >> 4;
    float cs[4] = {0.f, 0.f, 0.f, 0.f};
#pragma unroll
    for (int m = 0; m < 4; ++m) {
#pragma unroll
        for (int q = 0; q < 4; ++q) {
            int lr = wm * 64 + m * 16 + lg * 4 + q;
            float rsum = 0.f;
#pragma unroll
            for (int n = 0; n < 4; ++n) {
                int lc = wn * 64 + n * 16 + li;
                float v = acc[m][n][q];
                if (posT && lc == lr) { pos[brow + lr] = v; pos[bcol + lc] = v; }
                float e = (diag && lc == lr) ? 0.f : __expf(2.0f * v);
                rsum += e;
                cs[n] += e;
            }
            rsum += __shfl_xor(rsum, 1);
            rsum += __shfl_xor(rsum, 2);
            rsum += __shfl_xor(rsum, 4);
            rsum += __shfl_xor(rsum, 8);
            if (li == 0) atomicAdd(&rowsum[brow + lr], rsum);
        }
    }
    if (!diag) {
#pragma unroll
        for (int n = 0; n < 4; ++n) {
            float v = cs[n];
            v += __shfl_xor(v, 16);
            v += __shfl_xor(v, 32);
            if (lg == 0) atomicAdd(&rowsum[bcol + wn * 64 + n * 16 + li], v);
        }
    }
}

// -------- Phase 3: finalize scalar loss (also reduces kd/mse partials)
__global__ __launch_bounds__(256) void finalize(
    const float* __restrict__ rowsum, const float* __restrict__ pos,
    const float* __restrict__ kdp, const float* __restrict__ msep,
    float* __restrict__ out)
{
    const int tid = threadIdx.x;
    float c = 0.f;
    for (int i = tid; i < TWO_B; i += 256)
        c += logf(rowsum[i]) - 2.0f * pos[i];
    float kd = 0.f, ms = 0.f;
    for (int i = tid; i < 2048; i += 256) { kd += kdp[i]; ms += msep[i]; }
    c = waveReduceSum(c); kd = waveReduceSum(kd); ms = waveReduceSum(ms);
    __shared__ float sm[3][4];
    if ((tid & 63) == 0) { sm[0][tid >> 6] = c; sm[1][tid >> 6] = kd; sm[2][tid >> 6] = ms; }
    __syncthreads();
    if (tid == 0) {
        float cont = (sm[0][0] + sm[0][1] + sm[0][2] + sm[0][3]) / 4096.0f;
        float kds  = (sm[1][0] + sm[1][1] + sm[1][2] + sm[1][3]) / 2048.0f;
        float mses = (sm[2][0] + sm[2][1] + sm[2][2] + sm[2][3]) / (2048.0f * 4096.0f);
        out[0] = cont + kds + mses;
    }
}

extern "C" void kernel_launch(void* const* d_in, const int* in_sizes, int n_in,
                              void* d_out, int out_size, void* d_ws, size_t ws_size,
                              hipStream_t stream) {
    const float* et = (const float*)d_in[0];
    const float* es = (const float*)d_in[1];

    const size_t Z_BYTES = (size_t)TWO_B * DIM_;  // 16 MiB int8
    const size_t SMALL_FLOATS = 4096 * 3 + 2048 * 2 + 4096;
    const bool fast = ws_size >= Z_BYTES + SMALL_FLOATS * sizeof(float);

    if (fast) {
        char* z8 = (char*)d_ws;
        float* smallf = (float*)((char*)d_ws + Z_BYTES);
        float* rowsum = smallf;
        float* pos  = smallf + 4096;
        float* qs   = smallf + 4096 * 2;
        float* rinv = smallf + 4096 * 3;
        float* kdp  = smallf + 4096 * 4;
        float* msep = smallf + 4096 * 4 + 2048;
        hipMemsetAsync(rowsum, 0, 4096 * sizeof(float), stream);
        hipLaunchKernelGGL(row_stats, dim3(2048), dim3(256), 0, stream,
                           et, es, rinv, qs, kdp, msep, z8);
        hipLaunchKernelGGL(cont_gemm6, dim3(1056), dim3(128), 0, stream, z8, qs, rowsum, pos);
        hipLaunchKernelGGL(finalize, dim3(1), dim3(256), 0, stream, rowsum, pos, kdp, msep, (float*)d_out);
    } else {
        float* ws = (float*)d_ws;
        float* rowsum = ws;
        float* pos  = ws + 4096;
        float* qs   = ws + 4096 * 2;
        float* rinv = ws + 4096 * 3;
        float* kdp  = ws + 4096 * 4;
        float* msep = ws + 4096 * 4 + 2048;
        hipMemsetAsync(rowsum, 0, 4096 * sizeof(float), stream);
        hipLaunchKernelGGL(row_stats, dim3(2048), dim3(256), 0, stream,
                           et, es, rinv, qs, kdp, msep, (char*)nullptr);
        hipLaunchKernelGGL(cont_gemm, dim3(528), dim3(256), 0, stream, et, es, rinv, rowsum, pos);
        hipLaunchKernelGGL(finalize, dim3(1), dim3(256), 0, stream, rowsum, pos, kdp, msep, (float*)d_out);
    }
}